// Round 11
// baseline (631.701 us; speedup 1.0000x reference)
//
#include <hip/hip_runtime.h>

#define N_NODES 100000
#define D 64
#define BSZ 128           // nodes per bucket: dst>>7
#define NBUCK 782         // ceil(100000/128)
#define NBLK_A 256        // blocks in count/place passes
#define GCNT_N (NBUCK * NBLK_A)            // 200192
#define NCHUNK ((GCNT_N + 255) / 256)      // 782
#define NTILE (N_NODES / 32)               // 3125 exact
#define LPAD 65           // f32 stride in lacc: bank (n+f)%32

typedef __attribute__((ext_vector_type(8))) short short8;
typedef __attribute__((ext_vector_type(16))) float f32x16;
union Pack8 { uint4 u; short8 s; };

__device__ __forceinline__ unsigned f2bf(float f) {  // RNE float->bf16 bits
  unsigned u = __float_as_uint(f);
  return (u + 0x7fffu + ((u >> 16) & 1u)) >> 16;
}
#define BF_LO(u) __uint_as_float(((unsigned)(u)) << 16)
#define BF_HI(u) __uint_as_float(((unsigned)(u)) & 0xffff0000u)

// ---------- bucketed edge sort (LDS atomics only) ----------

__global__ __launch_bounds__(256) void passA_count(const int* __restrict__ dst,
                                                   int* __restrict__ gcnt,
                                                   int nE, int ec) {
  __shared__ int cnt[NBUCK];
  int t = threadIdx.x, blk = blockIdx.x;
  for (int i = t; i < NBUCK; i += 256) cnt[i] = 0;
  __syncthreads();
  int e0 = blk * ec, e1 = min(e0 + ec, nE);
  for (int e = e0 + t; e < e1; e += 256) atomicAdd(&cnt[dst[e] >> 7], 1);
  __syncthreads();
  for (int b = t; b < NBUCK; b += 256) gcnt[b * NBLK_A + blk] = cnt[b];
}

__global__ void gscan_p1(const int* __restrict__ g, int* __restrict__ csum) {
  int t = threadIdx.x, b = blockIdx.x;
  int i = b * 256 + t;
  int v = (i < GCNT_N) ? g[i] : 0;
  for (int off = 32; off; off >>= 1) v += __shfl_down(v, off);
  __shared__ int ws4[4];
  if ((t & 63) == 0) ws4[t >> 6] = v;
  __syncthreads();
  if (t == 0) csum[b] = ws4[0] + ws4[1] + ws4[2] + ws4[3];
}

__global__ void gscan_p2(int* __restrict__ csum, int nB) {
  __shared__ int s[1024];
  int t = threadIdx.x;
  int orig = (t < nB) ? csum[t] : 0;
  s[t] = orig;
  __syncthreads();
  for (int off = 1; off < 1024; off <<= 1) {
    int v = (t >= off) ? s[t - off] : 0;
    __syncthreads();
    s[t] += v;
    __syncthreads();
  }
  if (t < nB) csum[t] = s[t] - orig;  // exclusive block offsets
}

__global__ void gscan_p3(int* __restrict__ g, const int* __restrict__ csum) {
  __shared__ int s[256];
  int t = threadIdx.x, b = blockIdx.x;
  int i = b * 256 + t;
  int d = (i < GCNT_N) ? g[i] : 0;
  s[t] = d;
  __syncthreads();
  for (int off = 1; off < 256; off <<= 1) {
    int v = (t >= off) ? s[t - off] : 0;
    __syncthreads();
    s[t] += v;
    __syncthreads();
  }
  if (i < GCNT_N) g[i] = s[t] - d + csum[b];  // exclusive
}

__global__ __launch_bounds__(256) void passC_place(const int* __restrict__ src,
                                                   const int* __restrict__ dst,
                                                   const int* __restrict__ S,
                                                   uint2* __restrict__ pairs,
                                                   int nE, int ec) {
  __shared__ int cur[NBUCK];
  int t = threadIdx.x, blk = blockIdx.x;
  for (int b = t; b < NBUCK; b += 256) cur[b] = S[b * NBLK_A + blk];
  __syncthreads();
  int e0 = blk * ec, e1 = min(e0 + ec, nE);
  for (int e = e0 + t; e < e1; e += 256) {
    int d = dst[e];
    int p = atomicAdd(&cur[d >> 7], 1);
    pairs[p] = make_uint2((unsigned)d, (unsigned)src[e]);
  }
}

// ---------- Fold classifier through layer 2 ----------
__global__ void wfold_kernel(const float* __restrict__ Wc,
                             const float* __restrict__ Wl2,
                             const float* __restrict__ Wr2,
                             const float* __restrict__ bl2,
                             const float* __restrict__ bc,
                             float* __restrict__ A2, float* __restrict__ B2,
                             float* __restrict__ bfv) {
  int t = threadIdx.x;  // 128 threads
  int c = t >> 6, k = t & 63;
  float sa = 0.f, sb = 0.f;
  for (int j = 0; j < 64; ++j) {
    float w = Wc[c * 64 + j];
    sa = fmaf(w, Wl2[j * 64 + k], sa);
    sb = fmaf(w, Wr2[j * 64 + k], sb);
  }
  A2[c * 64 + k] = sa;
  B2[c * 64 + k] = sb;
  if (t < 2) {
    float s = bc[t];
    for (int j = 0; j < 64; ++j) s = fmaf(Wc[t * 64 + j], bl2[j], s);
    bfv[t] = s;
  }
}

// ---------- wprep: wcat = bf16(concat(Wl1, Wr1)) [128 x 64] ----------
__global__ void wprep_kernel(const float* __restrict__ Wl,
                             const float* __restrict__ Wr,
                             unsigned short* __restrict__ wcat) {
  int i = blockIdx.x * 256 + threadIdx.x;  // 8192 total
  if (i < 4096) wcat[i] = (unsigned short)f2bf(Wl[i]);
  else if (i < 8192) wcat[i] = (unsigned short)f2bf(Wr[i - 4096]);
}

// ---------- transform_mfma: t1 = x@Wl1^T (bf16), r1b = x@Wr1^T+b (bf16) ----
__global__ __launch_bounds__(256) void transform_mfma(
    const float* __restrict__ x, const unsigned short* __restrict__ wcat,
    const float* __restrict__ bl, unsigned short* __restrict__ t1,
    unsigned short* __restrict__ r1b) {
  int tid = threadIdx.x, lane = tid & 63;
  int l31 = lane & 31, hi = lane >> 5;

  short8 af[4][4];
#pragma unroll
  for (int jt = 0; jt < 4; ++jt)
#pragma unroll
    for (int kk = 0; kk < 4; ++kk)
      af[jt][kk] = *(const short8*)(wcat + (jt * 32 + l31) * 64 + kk * 16 + 8 * hi);

  const f32x16 Z = {0.f, 0.f, 0.f, 0.f, 0.f, 0.f, 0.f, 0.f,
                    0.f, 0.f, 0.f, 0.f, 0.f, 0.f, 0.f, 0.f};
  const float4* x4 = (const float4*)x;

  int gw = (blockIdx.x * 256 + tid) >> 6;
  int nW = (gridDim.x * 256) >> 6;

  for (int tile = gw; tile < NTILE; tile += nW) {
    int node = tile * 32 + l31;
    f32x16 acc[4] = {Z, Z, Z, Z};
#pragma unroll
    for (int kk = 0; kk < 4; ++kk) {
      float4 fa = x4[(size_t)node * 16 + kk * 4 + 2 * hi];
      float4 fb = x4[(size_t)node * 16 + kk * 4 + 2 * hi + 1];
      Pack8 pk;
      pk.u.x = f2bf(fa.x) | (f2bf(fa.y) << 16);
      pk.u.y = f2bf(fa.z) | (f2bf(fa.w) << 16);
      pk.u.z = f2bf(fb.x) | (f2bf(fb.y) << 16);
      pk.u.w = f2bf(fb.z) | (f2bf(fb.w) << 16);
      acc[0] = __builtin_amdgcn_mfma_f32_32x32x16_bf16(af[0][kk], pk.s, acc[0], 0, 0, 0);
      acc[1] = __builtin_amdgcn_mfma_f32_32x32x16_bf16(af[1][kk], pk.s, acc[1], 0, 0, 0);
      acc[2] = __builtin_amdgcn_mfma_f32_32x32x16_bf16(af[2][kk], pk.s, acc[2], 0, 0, 0);
      acc[3] = __builtin_amdgcn_mfma_f32_32x32x16_bf16(af[3][kk], pk.s, acc[3], 0, 0, 0);
    }
#pragma unroll
    for (int jt = 0; jt < 2; ++jt)
#pragma unroll
      for (int rg = 0; rg < 4; ++rg) {
        int j0 = jt * 32 + 8 * rg + 4 * hi;
        uint2 p;
        p.x = f2bf(acc[jt][4 * rg + 0]) | (f2bf(acc[jt][4 * rg + 1]) << 16);
        p.y = f2bf(acc[jt][4 * rg + 2]) | (f2bf(acc[jt][4 * rg + 3]) << 16);
        *(uint2*)(t1 + (size_t)node * 64 + j0) = p;
      }
#pragma unroll
    for (int jt = 2; jt < 4; ++jt)
#pragma unroll
      for (int rg = 0; rg < 4; ++rg) {
        int j0 = (jt - 2) * 32 + 8 * rg + 4 * hi;
        float4 bv = ((const float4*)bl)[j0 >> 2];
        uint2 p;
        p.x = f2bf(acc[jt][4 * rg + 0] + bv.x) |
              (f2bf(acc[jt][4 * rg + 1] + bv.y) << 16);
        p.y = f2bf(acc[jt][4 * rg + 2] + bv.z) |
              (f2bf(acc[jt][4 * rg + 3] + bv.w) << 16);
        *(uint2*)(r1b + (size_t)node * 64 + j0) = p;
      }
  }
}

// ---------- bucket_g1: edge-streaming layer-1 gather + epilogue ----------
// One block per 128-node bucket. Stream the bucket's pairs slice; each wave
// handles 64-edge groups (8 edges per t1 row-load, 8 lanes x 16B each),
// accumulating into LDS f32 via ds_add (lacc stride 65 -> bank (n+f)%32).
// Epilogue: mean + r1b + relu -> 4 projection dots -> g2, s2.
#define ATM8(dl, v)                                                 \
  { float* rp = &lacc[(dl) * LPAD + j8 * 8];                        \
    atomicAdd(rp + 0, BF_LO(v.x)); atomicAdd(rp + 1, BF_HI(v.x));   \
    atomicAdd(rp + 2, BF_LO(v.y)); atomicAdd(rp + 3, BF_HI(v.y));   \
    atomicAdd(rp + 4, BF_LO(v.z)); atomicAdd(rp + 5, BF_HI(v.z));   \
    atomicAdd(rp + 6, BF_LO(v.w)); atomicAdd(rp + 7, BF_HI(v.w)); }

__global__ __launch_bounds__(256) void bucket_g1(
    const uint2* __restrict__ pairs, const int* __restrict__ S,
    const unsigned short* __restrict__ t1,
    const unsigned short* __restrict__ r1b, const float* __restrict__ A2,
    const float* __restrict__ B2, float2* __restrict__ g2,
    float2* __restrict__ s2, int nE) {
  __shared__ float lacc[BSZ * LPAD];
  __shared__ int ldeg[BSZ];
  __shared__ float pAB[4][64];
  int t = threadIdx.x, b = blockIdx.x;
  for (int i = t; i < BSZ * LPAD; i += 256) lacc[i] = 0.f;
  if (t < BSZ) ldeg[t] = 0;
  pAB[t >> 6][t & 63] = (t < 128) ? A2[t] : B2[t - 128];
  __syncthreads();

  int base = S[b * NBLK_A];
  int end = (b == NBUCK - 1) ? nE : S[(b + 1) * NBLK_A];
  int lane = t & 63, w = t >> 6;
  int o = lane >> 3, j8 = lane & 7;

  for (int g0 = base + w * 64; g0 < end; g0 += 256) {
    int avail = min(end - g0, 64);
    uint2 pr = pairs[min(g0 + lane, nE - 1)];
#pragma unroll
    for (int s = 0; s < 8; s += 4) {
      // stage 4 sub-iters (32 edges): shfl meta + 4 independent row loads
      int e0 = s * 8 + o, e1 = e0 + 8, e2 = e0 + 16, e3 = e0 + 24;
      int d0 = __shfl((int)pr.x, e0), s0 = __shfl((int)pr.y, e0);
      int d1 = __shfl((int)pr.x, e1), s1 = __shfl((int)pr.y, e1);
      int d2 = __shfl((int)pr.x, e2), s2i = __shfl((int)pr.y, e2);
      int d3 = __shfl((int)pr.x, e3), s3 = __shfl((int)pr.y, e3);
      bool k0 = e0 < avail, k1 = e1 < avail, k2 = e2 < avail, k3 = e3 < avail;
      uint4 v0 = *(const uint4*)(t1 + (size_t)(k0 ? s0 : 0) * 64 + j8 * 8);
      uint4 v1 = *(const uint4*)(t1 + (size_t)(k1 ? s1 : 0) * 64 + j8 * 8);
      uint4 v2 = *(const uint4*)(t1 + (size_t)(k2 ? s2i : 0) * 64 + j8 * 8);
      uint4 v3 = *(const uint4*)(t1 + (size_t)(k3 ? s3 : 0) * 64 + j8 * 8);
      if (k0) { int dl = d0 & (BSZ - 1); ATM8(dl, v0); if (j8 == 0) atomicAdd(&ldeg[dl], 1); }
      if (k1) { int dl = d1 & (BSZ - 1); ATM8(dl, v1); if (j8 == 0) atomicAdd(&ldeg[dl], 1); }
      if (k2) { int dl = d2 & (BSZ - 1); ATM8(dl, v2); if (j8 == 0) atomicAdd(&ldeg[dl], 1); }
      if (k3) { int dl = d3 & (BSZ - 1); ATM8(dl, v3); if (j8 == 0) atomicAdd(&ldeg[dl], 1); }
    }
  }
  __syncthreads();

  // epilogue: wave w handles nodes w, w+4, ...; 64 lanes = 64 features
  for (int nl = w; nl < BSZ; nl += 4) {
    int node = b * BSZ + nl;
    if (node >= N_NODES) break;
    float inv = 1.f / (float)max(ldeg[nl], 1);
    float a = lacc[nl * LPAD + lane];
    unsigned rv = r1b[(size_t)node * 64 + lane];
    float h = fmaxf(fmaf(a, inv, BF_LO(rv)), 0.f);
    float d0 = h * pAB[0][lane];
    float d1 = h * pAB[1][lane];
    float d2 = h * pAB[2][lane];
    float d3 = h * pAB[3][lane];
#pragma unroll
    for (int off = 1; off < 64; off <<= 1) {
      d0 += __shfl_xor(d0, off);
      d1 += __shfl_xor(d1, off);
      d2 += __shfl_xor(d2, off);
      d3 += __shfl_xor(d3, off);
    }
    if (lane == 0) {
      g2[node] = make_float2(d0, d1);
      s2[node] = make_float2(d2, d3);
    }
  }
}

// ---------- bucket_g2: edge-streaming layer-2 gather -> out ----------
__global__ __launch_bounds__(256) void bucket_g2(
    const uint2* __restrict__ pairs, const int* __restrict__ S,
    const float2* __restrict__ g2, const float2* __restrict__ s2,
    const float* __restrict__ bfv, float* __restrict__ out, int nE) {
  __shared__ float o0[BSZ], o1[BSZ];
  __shared__ int ldeg[BSZ];
  int t = threadIdx.x, b = blockIdx.x;
  if (t < BSZ) { o0[t] = 0.f; o1[t] = 0.f; ldeg[t] = 0; }
  __syncthreads();
  int base = S[b * NBLK_A];
  int end = (b == NBUCK - 1) ? nE : S[(b + 1) * NBLK_A];
  for (int p = base + t; p < end; p += 256) {
    uint2 e = pairs[p];
    float2 v = g2[e.y];
    int dl = (int)(e.x & (BSZ - 1));
    atomicAdd(&o0[dl], v.x);
    atomicAdd(&o1[dl], v.y);
    atomicAdd(&ldeg[dl], 1);
  }
  __syncthreads();
  if (t < BSZ) {
    int node = b * BSZ + t;
    if (node < N_NODES) {
      float inv = 1.f / (float)max(ldeg[t], 1);
      float2 sv = s2[node];
      out[(size_t)node * 2 + 0] = fmaf(o0[t], inv, sv.x) + bfv[0];
      out[(size_t)node * 2 + 1] = fmaf(o1[t], inv, sv.y) + bfv[1];
    }
  }
}

extern "C" void kernel_launch(void* const* d_in, const int* in_sizes, int n_in,
                              void* d_out, int out_size, void* d_ws,
                              size_t ws_size, hipStream_t stream) {
  const float* x   = (const float*)d_in[0];
  const int*   ei  = (const int*)d_in[1];
  const float* Wl1 = (const float*)d_in[2];
  const float* bl1 = (const float*)d_in[3];
  const float* Wr1 = (const float*)d_in[4];
  const float* Wl2 = (const float*)d_in[5];
  const float* bl2 = (const float*)d_in[6];
  const float* Wr2 = (const float*)d_in[7];
  const float* Wc  = (const float*)d_in[8];
  const float* bc  = (const float*)d_in[9];
  float* out = (float*)d_out;

  int nE = in_sizes[1] / 2;
  const int* src = ei;
  const int* dst = ei + nE;

  // Workspace (~38 MB): pairs uint2[E] | t1 bf16[N*64] | r1b bf16[N*64] |
  // g2,s2 f2[N] | A2/B2/bf | wcat bf16[8192] | gcnt[GCNT_N] | csum[1024]
  uint2* pairs = (uint2*)d_ws;
  unsigned short* t1 = (unsigned short*)(pairs + nE);
  unsigned short* r1b = t1 + (size_t)N_NODES * D;
  float2* g2 = (float2*)(r1b + (size_t)N_NODES * D);
  float2* s2 = g2 + N_NODES;
  float* A2 = (float*)(s2 + N_NODES);
  float* B2 = A2 + 128;
  float* bfv = B2 + 128;
  unsigned short* wcat = (unsigned short*)(bfv + 4);
  int* gcnt = (int*)(wcat + 8192);
  int* csum = gcnt + GCNT_N;

  int ec = (nE + NBLK_A - 1) / NBLK_A;  // edges per count/place block

  passA_count<<<NBLK_A, 256, 0, stream>>>(dst, gcnt, nE, ec);
  gscan_p1<<<NCHUNK, 256, 0, stream>>>(gcnt, csum);
  gscan_p2<<<1, 1024, 0, stream>>>(csum, NCHUNK);
  gscan_p3<<<NCHUNK, 256, 0, stream>>>(gcnt, csum);
  passC_place<<<NBLK_A, 256, 0, stream>>>(src, dst, gcnt, pairs, nE, ec);

  wfold_kernel<<<1, 128, 0, stream>>>(Wc, Wl2, Wr2, bl2, bc, A2, B2, bfv);
  wprep_kernel<<<32, 256, 0, stream>>>(Wl1, Wr1, wcat);
  transform_mfma<<<512, 256, 0, stream>>>(x, wcat, bl1, t1, r1b);

  bucket_g1<<<NBUCK, 256, 0, stream>>>(pairs, gcnt, t1, r1b, A2, B2, g2, s2,
                                       nE);
  bucket_g2<<<NBUCK, 256, 0, stream>>>(pairs, gcnt, g2, s2, bfv, out, nE);
}

// Round 12
// 161.062 us; speedup vs baseline: 3.9221x; 3.9221x over previous
//
#include <hip/hip_runtime.h>

#define N_NODES 100000
#define D 64
#define NTILES 3125       // 32-node tiles: key = dst>>5 (100000/32 exact)
#define NBLK_A 256        // blocks in count/place passes
#define GCNT_N (NTILES * NBLK_A)           // 800000
#define NCHUNK ((GCNT_N + 255) / 256)      // 3125
#define NBUCK_D 391       // 256-node buckets for passD (8 tiles each)
#define NTILE_T (N_NODES / 32)             // transform tiles
#define TROW 72           // staged row stride in bf16 elems (144B, 16B-aligned)

typedef __attribute__((ext_vector_type(8))) short short8;
typedef __attribute__((ext_vector_type(16))) float f32x16;
union Pack8 { uint4 u; short8 s; };

__device__ __forceinline__ unsigned f2bf(float f) {  // RNE float->bf16 bits
  unsigned u = __float_as_uint(f);
  return (u + 0x7fffu + ((u >> 16) & 1u)) >> 16;
}
#define BF_LO(u) __uint_as_float(((unsigned)(u)) << 16)
#define BF_HI(u) __uint_as_float(((unsigned)(u)) & 0xffff0000u)

// ---------- counting sort by 32-node tile (LDS atomics only) ----------

__global__ __launch_bounds__(256) void passA_count(const int* __restrict__ dst,
                                                   int* __restrict__ gcnt,
                                                   int nE, int ec) {
  __shared__ int cnt[NTILES];
  int t = threadIdx.x, blk = blockIdx.x;
  for (int i = t; i < NTILES; i += 256) cnt[i] = 0;
  __syncthreads();
  int e0 = blk * ec, e1 = min(e0 + ec, nE);
  for (int e = e0 + t; e < e1; e += 256) atomicAdd(&cnt[dst[e] >> 5], 1);
  __syncthreads();
  for (int b = t; b < NTILES; b += 256) gcnt[b * NBLK_A + blk] = cnt[b];
}

__global__ void gscan_p1(const int* __restrict__ g, int* __restrict__ csum) {
  int t = threadIdx.x, b = blockIdx.x;
  int i = b * 256 + t;
  int v = (i < GCNT_N) ? g[i] : 0;
  for (int off = 32; off; off >>= 1) v += __shfl_down(v, off);
  __shared__ int ws4[4];
  if ((t & 63) == 0) ws4[t >> 6] = v;
  __syncthreads();
  if (t == 0) csum[b] = ws4[0] + ws4[1] + ws4[2] + ws4[3];
}

// single block, loops 1024-wide over nB chunk sums with carry
__global__ void gscan_p2(int* __restrict__ csum, int nB) {
  __shared__ int s[1024];
  int t = threadIdx.x;
  int carry = 0;
  for (int c0 = 0; c0 < nB; c0 += 1024) {
    int i = c0 + t;
    int orig = (i < nB) ? csum[i] : 0;
    s[t] = orig;
    __syncthreads();
    for (int off = 1; off < 1024; off <<= 1) {
      int v = (t >= off) ? s[t - off] : 0;
      __syncthreads();
      s[t] += v;
      __syncthreads();
    }
    if (i < nB) csum[i] = s[t] - orig + carry;
    int tot = s[1023];
    __syncthreads();
    carry += tot;
  }
}

__global__ void gscan_p3(int* __restrict__ g, const int* __restrict__ csum) {
  __shared__ int s[256];
  int t = threadIdx.x, b = blockIdx.x;
  int i = b * 256 + t;
  int d = (i < GCNT_N) ? g[i] : 0;
  s[t] = d;
  __syncthreads();
  for (int off = 1; off < 256; off <<= 1) {
    int v = (t >= off) ? s[t - off] : 0;
    __syncthreads();
    s[t] += v;
    __syncthreads();
  }
  if (i < GCNT_N) g[i] = s[t] - d + csum[b];  // exclusive
}

__global__ __launch_bounds__(256) void passC_place(const int* __restrict__ src,
                                                   const int* __restrict__ dst,
                                                   const int* __restrict__ S,
                                                   uint2* __restrict__ pairs,
                                                   int nE, int ec) {
  __shared__ int cur[NTILES];
  int t = threadIdx.x, blk = blockIdx.x;
  for (int b = t; b < NTILES; b += 256) cur[b] = S[b * NBLK_A + blk];
  __syncthreads();
  int e0 = blk * ec, e1 = min(e0 + ec, nE);
  for (int e = e0 + t; e < e1; e += 256) {
    int d = dst[e];
    int p = atomicAdd(&cur[d >> 5], 1);
    pairs[p] = make_uint2((unsigned)d, (unsigned)src[e]);
  }
}

// Pass D: per 256-node bucket (8 tiles) -> rowstart/deg/adj for gather2.
__global__ __launch_bounds__(256) void passD_csr(const uint2* __restrict__ pairs,
                                                 const int* __restrict__ S,
                                                 int* __restrict__ rowstart,
                                                 int* __restrict__ degI,
                                                 int* __restrict__ adj, int nE) {
  __shared__ int lh[256];
  __shared__ int sc[256];
  __shared__ int cur[256];
  int t = threadIdx.x, b = blockIdx.x;
  int base = S[(b * 8) * NBLK_A];
  int end = (b == NBUCK_D - 1) ? nE : S[((b + 1) * 8) * NBLK_A];
  lh[t] = 0;
  __syncthreads();
  for (int p = base + t; p < end; p += 256) atomicAdd(&lh[pairs[p].x & 255], 1);
  __syncthreads();
  int d = lh[t];
  sc[t] = d;
  __syncthreads();
  for (int off = 1; off < 256; off <<= 1) {
    int v = (t >= off) ? sc[t - off] : 0;
    __syncthreads();
    sc[t] += v;
    __syncthreads();
  }
  int ex = sc[t] - d;
  int node = b * 256 + t;
  if (node < N_NODES) {
    rowstart[node] = base + ex;
    degI[node] = d;
  }
  cur[t] = base + ex;
  __syncthreads();
  for (int p = base + t; p < end; p += 256) {
    uint2 e = pairs[p];
    int slot = atomicAdd(&cur[e.x & 255], 1);
    adj[slot] = (int)e.y;
  }
}

// ---------- Fold classifier through layer 2 ----------
__global__ void wfold_kernel(const float* __restrict__ Wc,
                             const float* __restrict__ Wl2,
                             const float* __restrict__ Wr2,
                             const float* __restrict__ bl2,
                             const float* __restrict__ bc,
                             float* __restrict__ A2, float* __restrict__ B2,
                             float* __restrict__ bfv) {
  int t = threadIdx.x;  // 128 threads
  int c = t >> 6, k = t & 63;
  float sa = 0.f, sb = 0.f;
  for (int j = 0; j < 64; ++j) {
    float w = Wc[c * 64 + j];
    sa = fmaf(w, Wl2[j * 64 + k], sa);
    sb = fmaf(w, Wr2[j * 64 + k], sb);
  }
  A2[c * 64 + k] = sa;
  B2[c * 64 + k] = sb;
  if (t < 2) {
    float s = bc[t];
    for (int j = 0; j < 64; ++j) s = fmaf(Wc[t * 64 + j], bl2[j], s);
    bfv[t] = s;
  }
}

// ---------- wprep: wcat = bf16(concat(Wl1, Wr1)) [128 x 64] ----------
__global__ void wprep_kernel(const float* __restrict__ Wl,
                             const float* __restrict__ Wr,
                             unsigned short* __restrict__ wcat) {
  int i = blockIdx.x * 256 + threadIdx.x;
  if (i < 4096) wcat[i] = (unsigned short)f2bf(Wl[i]);
  else if (i < 8192) wcat[i] = (unsigned short)f2bf(Wr[i - 4096]);
}

// ---------- transform_mfma: t1 = x@Wl1^T (bf16), r1b = x@Wr1^T+b (bf16) ----
__global__ __launch_bounds__(256) void transform_mfma(
    const float* __restrict__ x, const unsigned short* __restrict__ wcat,
    const float* __restrict__ bl, unsigned short* __restrict__ t1,
    unsigned short* __restrict__ r1b) {
  int tid = threadIdx.x, lane = tid & 63;
  int l31 = lane & 31, hi = lane >> 5;

  short8 af[4][4];
#pragma unroll
  for (int jt = 0; jt < 4; ++jt)
#pragma unroll
    for (int kk = 0; kk < 4; ++kk)
      af[jt][kk] = *(const short8*)(wcat + (jt * 32 + l31) * 64 + kk * 16 + 8 * hi);

  const f32x16 Z = {0.f, 0.f, 0.f, 0.f, 0.f, 0.f, 0.f, 0.f,
                    0.f, 0.f, 0.f, 0.f, 0.f, 0.f, 0.f, 0.f};
  const float4* x4 = (const float4*)x;

  int gw = (blockIdx.x * 256 + tid) >> 6;
  int nW = (gridDim.x * 256) >> 6;

  for (int tile = gw; tile < NTILE_T; tile += nW) {
    int node = tile * 32 + l31;
    f32x16 acc[4] = {Z, Z, Z, Z};
#pragma unroll
    for (int kk = 0; kk < 4; ++kk) {
      float4 fa = x4[(size_t)node * 16 + kk * 4 + 2 * hi];
      float4 fb = x4[(size_t)node * 16 + kk * 4 + 2 * hi + 1];
      Pack8 pk;
      pk.u.x = f2bf(fa.x) | (f2bf(fa.y) << 16);
      pk.u.y = f2bf(fa.z) | (f2bf(fa.w) << 16);
      pk.u.z = f2bf(fb.x) | (f2bf(fb.y) << 16);
      pk.u.w = f2bf(fb.z) | (f2bf(fb.w) << 16);
      acc[0] = __builtin_amdgcn_mfma_f32_32x32x16_bf16(af[0][kk], pk.s, acc[0], 0, 0, 0);
      acc[1] = __builtin_amdgcn_mfma_f32_32x32x16_bf16(af[1][kk], pk.s, acc[1], 0, 0, 0);
      acc[2] = __builtin_amdgcn_mfma_f32_32x32x16_bf16(af[2][kk], pk.s, acc[2], 0, 0, 0);
      acc[3] = __builtin_amdgcn_mfma_f32_32x32x16_bf16(af[3][kk], pk.s, acc[3], 0, 0, 0);
    }
#pragma unroll
    for (int jt = 0; jt < 2; ++jt)
#pragma unroll
      for (int rg = 0; rg < 4; ++rg) {
        int j0 = jt * 32 + 8 * rg + 4 * hi;
        uint2 p;
        p.x = f2bf(acc[jt][4 * rg + 0]) | (f2bf(acc[jt][4 * rg + 1]) << 16);
        p.y = f2bf(acc[jt][4 * rg + 2]) | (f2bf(acc[jt][4 * rg + 3]) << 16);
        *(uint2*)(t1 + (size_t)node * 64 + j0) = p;
      }
#pragma unroll
    for (int jt = 2; jt < 4; ++jt)
#pragma unroll
      for (int rg = 0; rg < 4; ++rg) {
        int j0 = (jt - 2) * 32 + 8 * rg + 4 * hi;
        float4 bv = ((const float4*)bl)[j0 >> 2];
        uint2 p;
        p.x = f2bf(acc[jt][4 * rg + 0] + bv.x) |
              (f2bf(acc[jt][4 * rg + 1] + bv.y) << 16);
        p.y = f2bf(acc[jt][4 * rg + 2] + bv.z) |
              (f2bf(acc[jt][4 * rg + 3] + bv.w) << 16);
        *(uint2*)(r1b + (size_t)node * 64 + j0) = p;
      }
  }
}

// ---------- tile_g1: MFMA indicator-gather, one wave per 32-dst tile -------
// Per 16-edge group: stage 16 t1 rows into LDS (2 coalesced uint4 wave-loads,
// ds_write_b128), read transposed as MFMA A-operand (A[feat][k], conflict-
// free u16 reads), build one-hot B-operand (B[k][dst&31]) from shfl'd dst,
// D[feat][dst] += A x B. Lane (l31,hi) ends owning node l31's 32 features.
__global__ __launch_bounds__(256) void tile_g1(
    const uint2* __restrict__ pairs, const int* __restrict__ S,
    const unsigned short* __restrict__ t1,
    const unsigned short* __restrict__ r1b, const float* __restrict__ A2,
    const float* __restrict__ B2, float2* __restrict__ g2,
    float2* __restrict__ s2, int nE) {
  __shared__ float pAB[4][64];
  __shared__ unsigned short stg[4][2][16 * TROW];
  int t = threadIdx.x, lane = t & 63, w = t >> 6;
  pAB[t >> 6][t & 63] = (t < 128) ? A2[t] : B2[t - 128];
  __syncthreads();

  int tile = blockIdx.x * 4 + w;
  if (tile >= NTILES) return;
  int base = S[tile * NBLK_A];
  int end = (tile == NTILES - 1) ? nE : S[(tile + 1) * NBLK_A];
  int l31 = lane & 31, hi = lane >> 5;
  int o = lane >> 3, j8 = lane & 7;
  unsigned short* st0 = &stg[w][0][0];
  unsigned short* st1 = &stg[w][1][0];

  const f32x16 Z = {0.f, 0.f, 0.f, 0.f, 0.f, 0.f, 0.f, 0.f,
                    0.f, 0.f, 0.f, 0.f, 0.f, 0.f, 0.f, 0.f};
  f32x16 acc0 = Z, acc1 = Z;
  int degc = 0;
  int ng = (end > base) ? ((end - base + 15) >> 4) : 0;

  uint2 pr = make_uint2(0u, 0u);
  int cnt = 0;
  uint4 v0 = make_uint4(0, 0, 0, 0), v1 = make_uint4(0, 0, 0, 0);
  if (ng > 0) {
    pr = pairs[min(base + (lane & 15), nE - 1)];
    cnt = min(end - base, 16);
    int sv0 = __shfl((int)pr.y, o);
    int sv1 = __shfl((int)pr.y, 8 + o);
    v0 = *(const uint4*)(t1 + (size_t)((o < cnt) ? sv0 : 0) * 64 + j8 * 8);
    v1 = *(const uint4*)(t1 + (size_t)((8 + o < cnt) ? sv1 : 0) * 64 + j8 * 8);
  }

  for (int gg = 0; gg < ng; ++gg) {
    unsigned short* st = (gg & 1) ? st1 : st0;
    // stage current group's rows (wave-private LDS, ds ops in-order)
    *(uint4*)(st + o * TROW + j8 * 8) = v0;
    *(uint4*)(st + (8 + o) * TROW + j8 * 8) = v1;
    // indicator B-frag from current pr/cnt: B[8hi+m][l31]
    unsigned am[8];
#pragma unroll
    for (int m = 0; m < 8; ++m) {
      int e = 8 * hi + m;
      int dv = __shfl((int)pr.x, e);
      bool ok = (e < cnt) && ((dv & 31) == l31);
      am[m] = ok ? 0x3F80u : 0u;
      degc += (am[m] >> 7) & 1;
    }
    Pack8 I;
    I.u.x = am[0] | (am[1] << 16);
    I.u.y = am[2] | (am[3] << 16);
    I.u.z = am[4] | (am[5] << 16);
    I.u.w = am[6] | (am[7] << 16);
    // prefetch next group's pairs + rows
    if (gg + 1 < ng) {
      int nb = base + (gg + 1) * 16;
      pr = pairs[min(nb + (lane & 15), nE - 1)];
      cnt = min(end - nb, 16);
      int sv0 = __shfl((int)pr.y, o);
      int sv1 = __shfl((int)pr.y, 8 + o);
      v0 = *(const uint4*)(t1 + (size_t)((o < cnt) ? sv0 : 0) * 64 + j8 * 8);
      v1 = *(const uint4*)(t1 + (size_t)((8 + o < cnt) ? sv1 : 0) * 64 + j8 * 8);
    }
    // A-frags: A[feat = fb*32+l31][k = 8hi+m] = staged[8hi+m][fb*32+l31]
    Pack8 Afrag0, Afrag1;
    {
      unsigned short b0[8], b1[8];
#pragma unroll
      for (int m = 0; m < 8; ++m) {
        b0[m] = st[(8 * hi + m) * TROW + l31];
        b1[m] = st[(8 * hi + m) * TROW + 32 + l31];
      }
      Afrag0.u.x = b0[0] | ((unsigned)b0[1] << 16);
      Afrag0.u.y = b0[2] | ((unsigned)b0[3] << 16);
      Afrag0.u.z = b0[4] | ((unsigned)b0[5] << 16);
      Afrag0.u.w = b0[6] | ((unsigned)b0[7] << 16);
      Afrag1.u.x = b1[0] | ((unsigned)b1[1] << 16);
      Afrag1.u.y = b1[2] | ((unsigned)b1[3] << 16);
      Afrag1.u.z = b1[4] | ((unsigned)b1[5] << 16);
      Afrag1.u.w = b1[6] | ((unsigned)b1[7] << 16);
    }
    acc0 = __builtin_amdgcn_mfma_f32_32x32x16_bf16(Afrag0.s, I.s, acc0, 0, 0, 0);
    acc1 = __builtin_amdgcn_mfma_f32_32x32x16_bf16(Afrag1.s, I.s, acc1, 0, 0, 0);
  }

  // epilogue: lane (l31,hi) holds D[feat][node=tile*32+l31], feat rows
  // (rg&3)+8*(rg>>2)+4*hi per fblock
  float degf = (float)(degc + __shfl_xor(degc, 32));
  float inv = 1.f / fmaxf(degf, 1.f);
  int node = tile * 32 + l31;
  float d0 = 0.f, d1 = 0.f, d2 = 0.f, d3 = 0.f;
#pragma unroll
  for (int fb = 0; fb < 2; ++fb) {
#pragma unroll
    for (int q4 = 0; q4 < 4; ++q4) {
      int f0 = fb * 32 + q4 * 8 + 4 * hi;
      uint2 rv = *(const uint2*)(r1b + (size_t)node * 64 + f0);
      float bias[4] = {BF_LO(rv.x), BF_HI(rv.x), BF_LO(rv.y), BF_HI(rv.y)};
#pragma unroll
      for (int j = 0; j < 4; ++j) {
        float a = fb ? acc1[q4 * 4 + j] : acc0[q4 * 4 + j];
        float hv = fmaxf(fmaf(a, inv, bias[j]), 0.f);
        int f = f0 + j;
        d0 = fmaf(hv, pAB[0][f], d0);
        d1 = fmaf(hv, pAB[1][f], d1);
        d2 = fmaf(hv, pAB[2][f], d2);
        d3 = fmaf(hv, pAB[3][f], d3);
      }
    }
  }
  d0 += __shfl_xor(d0, 32);
  d1 += __shfl_xor(d1, 32);
  d2 += __shfl_xor(d2, 32);
  d3 += __shfl_xor(d3, 32);
  if (hi == 0) {
    g2[node] = make_float2(d0, d1);
    s2[node] = make_float2(d2, d3);
  }
}

// ---------- gather2: out[n] = mean_j(g2[j]) + s2[n] + bf ----------
__global__ __launch_bounds__(256) void gather2_kernel(
    const int* __restrict__ rowstart, const int* __restrict__ degI,
    const int* __restrict__ adj, const float2* __restrict__ g2,
    const float2* __restrict__ s2, const float* __restrict__ bfv,
    float* __restrict__ out, int nE) {
  int tid = threadIdx.x, lane = tid & 63;
  int q = lane >> 4, l16 = lane & 15;
  float bf0 = bfv[0], bf1 = bfv[1];
  int gq = ((blockIdx.x * 256 + tid) >> 6) * 4 + q;
  int strideN = ((gridDim.x * 256) >> 6) * 4;
  for (int n = gq; n < N_NODES; n += strideN) {
    int rs = rowstart[n], dg = degI[n];
    float s0 = 0.f, s1 = 0.f;
    for (int base = 0; base < dg; base += 16) {
      int e = base + l16;
      int a = adj[min(rs + ((e < dg) ? e : 0), nE - 1)];
      float2 v = g2[a];
      float m = (e < dg) ? 1.f : 0.f;
      s0 = fmaf(v.x, m, s0);
      s1 = fmaf(v.y, m, s1);
    }
    s0 += __shfl_xor(s0, 1); s0 += __shfl_xor(s0, 2);
    s0 += __shfl_xor(s0, 4); s0 += __shfl_xor(s0, 8);
    s1 += __shfl_xor(s1, 1); s1 += __shfl_xor(s1, 2);
    s1 += __shfl_xor(s1, 4); s1 += __shfl_xor(s1, 8);
    if (l16 == 0) {
      float inv = 1.f / (float)max(dg, 1);
      float2 sv = s2[n];
      out[(size_t)n * 2 + 0] = fmaf(s0, inv, sv.x) + bf0;
      out[(size_t)n * 2 + 1] = fmaf(s1, inv, sv.y) + bf1;
    }
  }
}

extern "C" void kernel_launch(void* const* d_in, const int* in_sizes, int n_in,
                              void* d_out, int out_size, void* d_ws,
                              size_t ws_size, hipStream_t stream) {
  const float* x   = (const float*)d_in[0];
  const int*   ei  = (const int*)d_in[1];
  const float* Wl1 = (const float*)d_in[2];
  const float* bl1 = (const float*)d_in[3];
  const float* Wr1 = (const float*)d_in[4];
  const float* Wl2 = (const float*)d_in[5];
  const float* bl2 = (const float*)d_in[6];
  const float* Wr2 = (const float*)d_in[7];
  const float* Wc  = (const float*)d_in[8];
  const float* bc  = (const float*)d_in[9];
  float* out = (float*)d_out;

  int nE = in_sizes[1] / 2;
  const int* src = ei;
  const int* dst = ei + nE;

  // Workspace (~46 MB): pairs uint2[E] | t1 bf16[N*64] | r1b bf16[N*64] |
  // g2,s2 f2[N] | A2/B2/bf | wcat | degI,rowstart [N] | gcnt[800k] |
  // csum[4096] | adj[E]
  uint2* pairs = (uint2*)d_ws;
  unsigned short* t1 = (unsigned short*)(pairs + nE);
  unsigned short* r1b = t1 + (size_t)N_NODES * D;
  float2* g2 = (float2*)(r1b + (size_t)N_NODES * D);
  float2* s2 = g2 + N_NODES;
  float* A2 = (float*)(s2 + N_NODES);
  float* B2 = A2 + 128;
  float* bfv = B2 + 128;
  unsigned short* wcat = (unsigned short*)(bfv + 4);
  int* degI = (int*)(wcat + 8192);
  int* rowstart = degI + N_NODES;
  int* gcnt = rowstart + N_NODES;
  int* csum = gcnt + GCNT_N;
  int* adj = csum + 4096;

  int ec = (nE + NBLK_A - 1) / NBLK_A;

  passA_count<<<NBLK_A, 256, 0, stream>>>(dst, gcnt, nE, ec);
  gscan_p1<<<NCHUNK, 256, 0, stream>>>(gcnt, csum);
  gscan_p2<<<1, 1024, 0, stream>>>(csum, NCHUNK);
  gscan_p3<<<NCHUNK, 256, 0, stream>>>(gcnt, csum);
  passC_place<<<NBLK_A, 256, 0, stream>>>(src, dst, gcnt, pairs, nE, ec);
  passD_csr<<<NBUCK_D, 256, 0, stream>>>(pairs, gcnt, rowstart, degI, adj, nE);

  wfold_kernel<<<1, 128, 0, stream>>>(Wc, Wl2, Wr2, bl2, bc, A2, B2, bfv);
  wprep_kernel<<<32, 256, 0, stream>>>(Wl1, Wr1, wcat);
  transform_mfma<<<512, 256, 0, stream>>>(x, wcat, bl1, t1, r1b);

  tile_g1<<<(NTILES + 3) / 4, 256, 0, stream>>>(pairs, gcnt, t1, r1b, A2, B2,
                                                g2, s2, nE);
  gather2_kernel<<<512, 256, 0, stream>>>(rowstart, degI, adj, g2, s2, bfv,
                                          out, nE);
}

// Round 13
// 144.480 us; speedup vs baseline: 4.3722x; 1.1148x over previous
//
#include <hip/hip_runtime.h>

#define N_NODES 100000
#define D 64
#define NTILES 3125       // 32-node output tiles for tile_g1
#define NBUCK 391         // 256-node buckets: dst>>8
#define NBLK_A 512        // blocks in count/place passes
#define GCNT_N (NBUCK * NBLK_A)            // 200192
#define NCHUNK ((GCNT_N + 255) / 256)      // 782
#define NTILE_T (N_NODES / 32)             // transform tiles
#define TROW 72           // staged row stride in bf16 elems (144B)

typedef __attribute__((ext_vector_type(8))) short short8;
typedef __attribute__((ext_vector_type(16))) float f32x16;
union Pack8 { uint4 u; short8 s; };

__device__ __forceinline__ unsigned f2bf(float f) {  // RNE float->bf16 bits
  unsigned u = __float_as_uint(f);
  return (u + 0x7fffu + ((u >> 16) & 1u)) >> 16;
}
#define BF_LO(u) __uint_as_float(((unsigned)(u)) << 16)
#define BF_HI(u) __uint_as_float(((unsigned)(u)) & 0xffff0000u)

// ---------- counting-sort to 256-node buckets, then per-node in passD ------

__global__ __launch_bounds__(256) void passA_count(const int* __restrict__ dst,
                                                   int* __restrict__ gcnt,
                                                   int nE, int ec) {
  __shared__ int cnt[NBUCK];
  int t = threadIdx.x, blk = blockIdx.x;
  for (int i = t; i < NBUCK; i += 256) cnt[i] = 0;
  __syncthreads();
  int e0 = blk * ec, e1 = min(e0 + ec, nE);
  for (int e = e0 + t; e < e1; e += 256) atomicAdd(&cnt[dst[e] >> 8], 1);
  __syncthreads();
  for (int b = t; b < NBUCK; b += 256) gcnt[b * NBLK_A + blk] = cnt[b];
}

__global__ void gscan_p1(const int* __restrict__ g, int* __restrict__ csum) {
  int t = threadIdx.x, b = blockIdx.x;
  int i = b * 256 + t;
  int v = (i < GCNT_N) ? g[i] : 0;
  for (int off = 32; off; off >>= 1) v += __shfl_down(v, off);
  __shared__ int ws4[4];
  if ((t & 63) == 0) ws4[t >> 6] = v;
  __syncthreads();
  if (t == 0) csum[b] = ws4[0] + ws4[1] + ws4[2] + ws4[3];
}

__global__ void gscan_p2(int* __restrict__ csum, int nB) {
  __shared__ int s[1024];
  int t = threadIdx.x;
  int orig = (t < nB) ? csum[t] : 0;
  s[t] = orig;
  __syncthreads();
  for (int off = 1; off < 1024; off <<= 1) {
    int v = (t >= off) ? s[t - off] : 0;
    __syncthreads();
    s[t] += v;
    __syncthreads();
  }
  if (t < nB) csum[t] = s[t] - orig;  // exclusive block offsets
}

__global__ void gscan_p3(int* __restrict__ g, const int* __restrict__ csum) {
  __shared__ int s[256];
  int t = threadIdx.x, b = blockIdx.x;
  int i = b * 256 + t;
  int d = (i < GCNT_N) ? g[i] : 0;
  s[t] = d;
  __syncthreads();
  for (int off = 1; off < 256; off <<= 1) {
    int v = (t >= off) ? s[t - off] : 0;
    __syncthreads();
    s[t] += v;
    __syncthreads();
  }
  if (i < GCNT_N) g[i] = s[t] - d + csum[b];  // exclusive
}

__global__ __launch_bounds__(256) void passC_place(const int* __restrict__ src,
                                                   const int* __restrict__ dst,
                                                   const int* __restrict__ S,
                                                   uint2* __restrict__ pairs,
                                                   int nE, int ec) {
  __shared__ int cur[NBUCK];
  int t = threadIdx.x, blk = blockIdx.x;
  for (int b = t; b < NBUCK; b += 256) cur[b] = S[b * NBLK_A + blk];
  __syncthreads();
  int e0 = blk * ec, e1 = min(e0 + ec, nE);
  for (int e = e0 + t; e < e1; e += 256) {
    int d = dst[e];
    int p = atomicAdd(&cur[d >> 8], 1);
    pairs[p] = make_uint2((unsigned)d, (unsigned)src[e]);
  }
}

// Pass D: per 256-node bucket -> rowstart/deg + fully node-sorted pairs (srt).
__global__ __launch_bounds__(256) void passD_csr(const uint2* __restrict__ pairs,
                                                 const int* __restrict__ S,
                                                 int* __restrict__ rowstart,
                                                 int* __restrict__ degI,
                                                 uint2* __restrict__ srt,
                                                 int nE) {
  __shared__ int lh[256];
  __shared__ int sc[256];
  __shared__ int cur[256];
  int t = threadIdx.x, b = blockIdx.x;
  int base = S[b * NBLK_A];
  int end = (b == NBUCK - 1) ? nE : S[(b + 1) * NBLK_A];
  lh[t] = 0;
  __syncthreads();
  for (int p = base + t; p < end; p += 256) atomicAdd(&lh[pairs[p].x & 255], 1);
  __syncthreads();
  int d = lh[t];
  sc[t] = d;
  __syncthreads();
  for (int off = 1; off < 256; off <<= 1) {
    int v = (t >= off) ? sc[t - off] : 0;
    __syncthreads();
    sc[t] += v;
    __syncthreads();
  }
  int ex = sc[t] - d;
  int node = b * 256 + t;
  if (node < N_NODES) {
    rowstart[node] = base + ex;
    degI[node] = d;
  }
  cur[t] = base + ex;
  __syncthreads();
  for (int p = base + t; p < end; p += 256) {
    uint2 e = pairs[p];
    int slot = atomicAdd(&cur[e.x & 255], 1);
    srt[slot] = e;
  }
}

// ---------- Fold classifier through layer 2 ----------
__global__ void wfold_kernel(const float* __restrict__ Wc,
                             const float* __restrict__ Wl2,
                             const float* __restrict__ Wr2,
                             const float* __restrict__ bl2,
                             const float* __restrict__ bc,
                             float* __restrict__ A2, float* __restrict__ B2,
                             float* __restrict__ bfv) {
  int t = threadIdx.x;  // 128 threads
  int c = t >> 6, k = t & 63;
  float sa = 0.f, sb = 0.f;
  for (int j = 0; j < 64; ++j) {
    float w = Wc[c * 64 + j];
    sa = fmaf(w, Wl2[j * 64 + k], sa);
    sb = fmaf(w, Wr2[j * 64 + k], sb);
  }
  A2[c * 64 + k] = sa;
  B2[c * 64 + k] = sb;
  if (t < 2) {
    float s = bc[t];
    for (int j = 0; j < 64; ++j) s = fmaf(Wc[t * 64 + j], bl2[j], s);
    bfv[t] = s;
  }
}

// ---------- wprep: wcat = bf16(concat(Wl1, Wr1)) [128 x 64] ----------
__global__ void wprep_kernel(const float* __restrict__ Wl,
                             const float* __restrict__ Wr,
                             unsigned short* __restrict__ wcat) {
  int i = blockIdx.x * 256 + threadIdx.x;
  if (i < 4096) wcat[i] = (unsigned short)f2bf(Wl[i]);
  else if (i < 8192) wcat[i] = (unsigned short)f2bf(Wr[i - 4096]);
}

// ---------- transform_mfma: t1 = x@Wl1^T (bf16), r1b = x@Wr1^T+b (bf16) ----
__global__ __launch_bounds__(256) void transform_mfma(
    const float* __restrict__ x, const unsigned short* __restrict__ wcat,
    const float* __restrict__ bl, unsigned short* __restrict__ t1,
    unsigned short* __restrict__ r1b) {
  int tid = threadIdx.x, lane = tid & 63;
  int l31 = lane & 31, hi = lane >> 5;

  short8 af[4][4];
#pragma unroll
  for (int jt = 0; jt < 4; ++jt)
#pragma unroll
    for (int kk = 0; kk < 4; ++kk)
      af[jt][kk] = *(const short8*)(wcat + (jt * 32 + l31) * 64 + kk * 16 + 8 * hi);

  const f32x16 Z = {0.f, 0.f, 0.f, 0.f, 0.f, 0.f, 0.f, 0.f,
                    0.f, 0.f, 0.f, 0.f, 0.f, 0.f, 0.f, 0.f};
  const float4* x4 = (const float4*)x;

  int gw = (blockIdx.x * 256 + tid) >> 6;
  int nW = (gridDim.x * 256) >> 6;

  for (int tile = gw; tile < NTILE_T; tile += nW) {
    int node = tile * 32 + l31;
    f32x16 acc[4] = {Z, Z, Z, Z};
#pragma unroll
    for (int kk = 0; kk < 4; ++kk) {
      float4 fa = x4[(size_t)node * 16 + kk * 4 + 2 * hi];
      float4 fb = x4[(size_t)node * 16 + kk * 4 + 2 * hi + 1];
      Pack8 pk;
      pk.u.x = f2bf(fa.x) | (f2bf(fa.y) << 16);
      pk.u.y = f2bf(fa.z) | (f2bf(fa.w) << 16);
      pk.u.z = f2bf(fb.x) | (f2bf(fb.y) << 16);
      pk.u.w = f2bf(fb.z) | (f2bf(fb.w) << 16);
      acc[0] = __builtin_amdgcn_mfma_f32_32x32x16_bf16(af[0][kk], pk.s, acc[0], 0, 0, 0);
      acc[1] = __builtin_amdgcn_mfma_f32_32x32x16_bf16(af[1][kk], pk.s, acc[1], 0, 0, 0);
      acc[2] = __builtin_amdgcn_mfma_f32_32x32x16_bf16(af[2][kk], pk.s, acc[2], 0, 0, 0);
      acc[3] = __builtin_amdgcn_mfma_f32_32x32x16_bf16(af[3][kk], pk.s, acc[3], 0, 0, 0);
    }
#pragma unroll
    for (int jt = 0; jt < 2; ++jt)
#pragma unroll
      for (int rg = 0; rg < 4; ++rg) {
        int j0 = jt * 32 + 8 * rg + 4 * hi;
        uint2 p;
        p.x = f2bf(acc[jt][4 * rg + 0]) | (f2bf(acc[jt][4 * rg + 1]) << 16);
        p.y = f2bf(acc[jt][4 * rg + 2]) | (f2bf(acc[jt][4 * rg + 3]) << 16);
        *(uint2*)(t1 + (size_t)node * 64 + j0) = p;
      }
#pragma unroll
    for (int jt = 2; jt < 4; ++jt)
#pragma unroll
      for (int rg = 0; rg < 4; ++rg) {
        int j0 = (jt - 2) * 32 + 8 * rg + 4 * hi;
        float4 bv = ((const float4*)bl)[j0 >> 2];
        uint2 p;
        p.x = f2bf(acc[jt][4 * rg + 0] + bv.x) |
              (f2bf(acc[jt][4 * rg + 1] + bv.y) << 16);
        p.y = f2bf(acc[jt][4 * rg + 2] + bv.z) |
              (f2bf(acc[jt][4 * rg + 3] + bv.w) << 16);
        *(uint2*)(r1b + (size_t)node * 64 + j0) = p;
      }
  }
}

// ---------- tile_g1: MFMA indicator-gather, 2-group pipeline ----------
// One wave per 32-dst tile (ranges from rowstart). Per 16-edge group:
// stage 16 t1 rows to LDS (2 coalesced loads), transpose-read as MFMA A,
// one-hot indicator as B, D[feat][dst] += AxB. 2 groups/iter, prefetch
// 2 groups ahead -> 4 independent row-loads in flight per wave.
__global__ __launch_bounds__(256) void tile_g1(
    const uint2* __restrict__ srt, const int* __restrict__ rowstart,
    const unsigned short* __restrict__ t1,
    const unsigned short* __restrict__ r1b, const float* __restrict__ A2,
    const float* __restrict__ B2, float2* __restrict__ g2,
    float2* __restrict__ s2, int nE) {
  __shared__ float pAB[4][64];
  __shared__ unsigned short stg[4][2][16 * TROW];
  int t = threadIdx.x, lane = t & 63, w = t >> 6;
  pAB[t >> 6][t & 63] = (t < 128) ? A2[t] : B2[t - 128];
  __syncthreads();

  int tile = blockIdx.x * 4 + w;
  if (tile >= NTILES) return;
  int base = rowstart[tile * 32];
  int end = (tile == NTILES - 1) ? nE : rowstart[(tile + 1) * 32];
  int l31 = lane & 31, hi = lane >> 5;
  int o = lane >> 3, j8 = lane & 7;
  unsigned short* stA = &stg[w][0][0];
  unsigned short* stB = &stg[w][1][0];

  const f32x16 Z = {0.f, 0.f, 0.f, 0.f, 0.f, 0.f, 0.f, 0.f,
                    0.f, 0.f, 0.f, 0.f, 0.f, 0.f, 0.f, 0.f};
  f32x16 acc0 = Z, acc1 = Z;
  int degc = 0;
  int ng = (end > base) ? ((end - base + 15) >> 4) : 0;

  uint2 prA = make_uint2(0u, 0u), prB = make_uint2(0u, 0u);
  int cntA = 0, cntB = 0;
  uint4 vA0 = make_uint4(0, 0, 0, 0), vA1 = vA0, vB0 = vA0, vB1 = vA0;
  if (ng > 0) {
    prA = srt[min(base + (lane & 15), nE - 1)];
    cntA = min(end - base, 16);
    int s0 = __shfl((int)prA.y, o), s1 = __shfl((int)prA.y, 8 + o);
    vA0 = *(const uint4*)(t1 + (size_t)((o < cntA) ? s0 : 0) * 64 + j8 * 8);
    vA1 = *(const uint4*)(t1 + (size_t)((8 + o < cntA) ? s1 : 0) * 64 + j8 * 8);
  }
  if (ng > 1) {
    int nb = base + 16;
    prB = srt[min(nb + (lane & 15), nE - 1)];
    cntB = min(end - nb, 16);
    int s0 = __shfl((int)prB.y, o), s1 = __shfl((int)prB.y, 8 + o);
    vB0 = *(const uint4*)(t1 + (size_t)((o < cntB) ? s0 : 0) * 64 + j8 * 8);
    vB1 = *(const uint4*)(t1 + (size_t)((8 + o < cntB) ? s1 : 0) * 64 + j8 * 8);
  }

  for (int gg = 0; gg < ng; gg += 2) {
    bool hasB = (gg + 1 < ng);
    // stage current groups (frees vA/vB regs)
    *(uint4*)(stA + o * TROW + j8 * 8) = vA0;
    *(uint4*)(stA + (8 + o) * TROW + j8 * 8) = vA1;
    if (hasB) {
      *(uint4*)(stB + o * TROW + j8 * 8) = vB0;
      *(uint4*)(stB + (8 + o) * TROW + j8 * 8) = vB1;
    }
    // indicators from current meta (before prefetch overwrites)
    unsigned amA[8], amB[8];
#pragma unroll
    for (int m = 0; m < 8; ++m) {
      int e = 8 * hi + m;
      int dv = __shfl((int)prA.x, e);
      bool ok = (e < cntA) && ((dv & 31) == l31);
      amA[m] = ok ? 0x3F80u : 0u;
      degc += (amA[m] >> 7) & 1;
    }
    if (hasB) {
#pragma unroll
      for (int m = 0; m < 8; ++m) {
        int e = 8 * hi + m;
        int dv = __shfl((int)prB.x, e);
        bool ok = (e < cntB) && ((dv & 31) == l31);
        amB[m] = ok ? 0x3F80u : 0u;
        degc += (amB[m] >> 7) & 1;
      }
    }
    // prefetch groups gg+2 / gg+3
    if (gg + 2 < ng) {
      int nb = base + (gg + 2) * 16;
      prA = srt[min(nb + (lane & 15), nE - 1)];
      cntA = min(end - nb, 16);
      int s0 = __shfl((int)prA.y, o), s1 = __shfl((int)prA.y, 8 + o);
      vA0 = *(const uint4*)(t1 + (size_t)((o < cntA) ? s0 : 0) * 64 + j8 * 8);
      vA1 = *(const uint4*)(t1 + (size_t)((8 + o < cntA) ? s1 : 0) * 64 + j8 * 8);
    }
    if (gg + 3 < ng) {
      int nb = base + (gg + 3) * 16;
      prB = srt[min(nb + (lane & 15), nE - 1)];
      cntB = min(end - nb, 16);
      int s0 = __shfl((int)prB.y, o), s1 = __shfl((int)prB.y, 8 + o);
      vB0 = *(const uint4*)(t1 + (size_t)((o < cntB) ? s0 : 0) * 64 + j8 * 8);
      vB1 = *(const uint4*)(t1 + (size_t)((8 + o < cntB) ? s1 : 0) * 64 + j8 * 8);
    }
    // group A: transpose-read + MFMA
    {
      Pack8 I;
      I.u.x = amA[0] | (amA[1] << 16);
      I.u.y = amA[2] | (amA[3] << 16);
      I.u.z = amA[4] | (amA[5] << 16);
      I.u.w = amA[6] | (amA[7] << 16);
      unsigned short b0[8], b1[8];
#pragma unroll
      for (int m = 0; m < 8; ++m) {
        b0[m] = stA[(8 * hi + m) * TROW + l31];
        b1[m] = stA[(8 * hi + m) * TROW + 32 + l31];
      }
      Pack8 F0, F1;
      F0.u.x = b0[0] | ((unsigned)b0[1] << 16);
      F0.u.y = b0[2] | ((unsigned)b0[3] << 16);
      F0.u.z = b0[4] | ((unsigned)b0[5] << 16);
      F0.u.w = b0[6] | ((unsigned)b0[7] << 16);
      F1.u.x = b1[0] | ((unsigned)b1[1] << 16);
      F1.u.y = b1[2] | ((unsigned)b1[3] << 16);
      F1.u.z = b1[4] | ((unsigned)b1[5] << 16);
      F1.u.w = b1[6] | ((unsigned)b1[7] << 16);
      acc0 = __builtin_amdgcn_mfma_f32_32x32x16_bf16(F0.s, I.s, acc0, 0, 0, 0);
      acc1 = __builtin_amdgcn_mfma_f32_32x32x16_bf16(F1.s, I.s, acc1, 0, 0, 0);
    }
    if (hasB) {
      Pack8 I;
      I.u.x = amB[0] | (amB[1] << 16);
      I.u.y = amB[2] | (amB[3] << 16);
      I.u.z = amB[4] | (amB[5] << 16);
      I.u.w = amB[6] | (amB[7] << 16);
      unsigned short b0[8], b1[8];
#pragma unroll
      for (int m = 0; m < 8; ++m) {
        b0[m] = stB[(8 * hi + m) * TROW + l31];
        b1[m] = stB[(8 * hi + m) * TROW + 32 + l31];
      }
      Pack8 F0, F1;
      F0.u.x = b0[0] | ((unsigned)b0[1] << 16);
      F0.u.y = b0[2] | ((unsigned)b0[3] << 16);
      F0.u.z = b0[4] | ((unsigned)b0[5] << 16);
      F0.u.w = b0[6] | ((unsigned)b0[7] << 16);
      F1.u.x = b1[0] | ((unsigned)b1[1] << 16);
      F1.u.y = b1[2] | ((unsigned)b1[3] << 16);
      F1.u.z = b1[4] | ((unsigned)b1[5] << 16);
      F1.u.w = b1[6] | ((unsigned)b1[7] << 16);
      acc0 = __builtin_amdgcn_mfma_f32_32x32x16_bf16(F0.s, I.s, acc0, 0, 0, 0);
      acc1 = __builtin_amdgcn_mfma_f32_32x32x16_bf16(F1.s, I.s, acc1, 0, 0, 0);
    }
  }

  // epilogue: lane (l31,hi) holds D[feat][node], feat = fb*32+(rg&..)+4*hi
  float degf = (float)(degc + __shfl_xor(degc, 32));
  float inv = 1.f / fmaxf(degf, 1.f);
  int node = tile * 32 + l31;
  float d0 = 0.f, d1 = 0.f, d2 = 0.f, d3 = 0.f;
#pragma unroll
  for (int fb = 0; fb < 2; ++fb) {
#pragma unroll
    for (int q4 = 0; q4 < 4; ++q4) {
      int f0 = fb * 32 + q4 * 8 + 4 * hi;
      uint2 rv = *(const uint2*)(r1b + (size_t)node * 64 + f0);
      float bias[4] = {BF_LO(rv.x), BF_HI(rv.x), BF_LO(rv.y), BF_HI(rv.y)};
#pragma unroll
      for (int j = 0; j < 4; ++j) {
        float a = fb ? acc1[q4 * 4 + j] : acc0[q4 * 4 + j];
        float hv = fmaxf(fmaf(a, inv, bias[j]), 0.f);
        int f = f0 + j;
        d0 = fmaf(hv, pAB[0][f], d0);
        d1 = fmaf(hv, pAB[1][f], d1);
        d2 = fmaf(hv, pAB[2][f], d2);
        d3 = fmaf(hv, pAB[3][f], d3);
      }
    }
  }
  d0 += __shfl_xor(d0, 32);
  d1 += __shfl_xor(d1, 32);
  d2 += __shfl_xor(d2, 32);
  d3 += __shfl_xor(d3, 32);
  if (hi == 0) {
    g2[node] = make_float2(d0, d1);
    s2[node] = make_float2(d2, d3);
  }
}

// ---------- gather2: out[n] = mean_j(g2[j]) + s2[n] + bf ----------
__global__ __launch_bounds__(256) void gather2_kernel(
    const int* __restrict__ rowstart, const int* __restrict__ degI,
    const uint2* __restrict__ srt, const float2* __restrict__ g2,
    const float2* __restrict__ s2, const float* __restrict__ bfv,
    float* __restrict__ out, int nE) {
  int tid = threadIdx.x, lane = tid & 63;
  int q = lane >> 4, l16 = lane & 15;
  float bf0 = bfv[0], bf1 = bfv[1];
  int gq = ((blockIdx.x * 256 + tid) >> 6) * 4 + q;
  int strideN = ((gridDim.x * 256) >> 6) * 4;
  for (int n = gq; n < N_NODES; n += strideN) {
    int rs = rowstart[n], dg = degI[n];
    float s0 = 0.f, s1 = 0.f;
    for (int base = 0; base < dg; base += 16) {
      int e = base + l16;
      int a = (int)srt[min(rs + ((e < dg) ? e : 0), nE - 1)].y;
      float2 v = g2[a];
      float m = (e < dg) ? 1.f : 0.f;
      s0 = fmaf(v.x, m, s0);
      s1 = fmaf(v.y, m, s1);
    }
    s0 += __shfl_xor(s0, 1); s0 += __shfl_xor(s0, 2);
    s0 += __shfl_xor(s0, 4); s0 += __shfl_xor(s0, 8);
    s1 += __shfl_xor(s1, 1); s1 += __shfl_xor(s1, 2);
    s1 += __shfl_xor(s1, 4); s1 += __shfl_xor(s1, 8);
    if (l16 == 0) {
      float inv = 1.f / (float)max(dg, 1);
      float2 sv = s2[n];
      out[(size_t)n * 2 + 0] = fmaf(s0, inv, sv.x) + bf0;
      out[(size_t)n * 2 + 1] = fmaf(s1, inv, sv.y) + bf1;
    }
  }
}

extern "C" void kernel_launch(void* const* d_in, const int* in_sizes, int n_in,
                              void* d_out, int out_size, void* d_ws,
                              size_t ws_size, hipStream_t stream) {
  const float* x   = (const float*)d_in[0];
  const int*   ei  = (const int*)d_in[1];
  const float* Wl1 = (const float*)d_in[2];
  const float* bl1 = (const float*)d_in[3];
  const float* Wr1 = (const float*)d_in[4];
  const float* Wl2 = (const float*)d_in[5];
  const float* bl2 = (const float*)d_in[6];
  const float* Wr2 = (const float*)d_in[7];
  const float* Wc  = (const float*)d_in[8];
  const float* bc  = (const float*)d_in[9];
  float* out = (float*)d_out;

  int nE = in_sizes[1] / 2;
  const int* src = ei;
  const int* dst = ei + nE;

  // Workspace (~40 MB): t1 bf16[N*64] (aliases pairs uint2[E]; pairs dead
  // before transform writes t1) | srt uint2[E] | r1b bf16[N*64] | g2,s2 |
  // A2/B2/bf | wcat | degI,rowstart [N] | gcnt[200k] | csum[1024]
  unsigned short* t1 = (unsigned short*)d_ws;
  uint2* pairs = (uint2*)d_ws;  // alias with t1
  uint2* srt = (uint2*)(t1 + (size_t)N_NODES * D);
  unsigned short* r1b = (unsigned short*)(srt + nE);
  float2* g2 = (float2*)(r1b + (size_t)N_NODES * D);
  float2* s2 = g2 + N_NODES;
  float* A2 = (float*)(s2 + N_NODES);
  float* B2 = A2 + 128;
  float* bfv = B2 + 128;
  unsigned short* wcat = (unsigned short*)(bfv + 4);
  int* degI = (int*)(wcat + 8192);
  int* rowstart = degI + N_NODES;
  int* gcnt = rowstart + N_NODES;
  int* csum = gcnt + GCNT_N;

  int ec = (nE + NBLK_A - 1) / NBLK_A;

  passA_count<<<NBLK_A, 256, 0, stream>>>(dst, gcnt, nE, ec);
  gscan_p1<<<NCHUNK, 256, 0, stream>>>(gcnt, csum);
  gscan_p2<<<1, 1024, 0, stream>>>(csum, NCHUNK);
  gscan_p3<<<NCHUNK, 256, 0, stream>>>(gcnt, csum);
  passC_place<<<NBLK_A, 256, 0, stream>>>(src, dst, gcnt, pairs, nE, ec);
  passD_csr<<<NBUCK, 256, 0, stream>>>(pairs, gcnt, rowstart, degI, srt, nE);

  wfold_kernel<<<1, 128, 0, stream>>>(Wc, Wl2, Wr2, bl2, bc, A2, B2, bfv);
  wprep_kernel<<<32, 256, 0, stream>>>(Wl1, Wr1, wcat);
  transform_mfma<<<512, 256, 0, stream>>>(x, wcat, bl1, t1, r1b);

  tile_g1<<<(NTILES + 3) / 4, 256, 0, stream>>>(srt, rowstart, t1, r1b, A2,
                                                B2, g2, s2, nE);
  gather2_kernel<<<512, 256, 0, stream>>>(rowstart, degI, srt, g2, s2, bfv,
                                          out, nE);
}

// Round 14
// 143.460 us; speedup vs baseline: 4.4033x; 1.0071x over previous
//
#include <hip/hip_runtime.h>

#define N_NODES 100000
#define D 64
#define NTILES 3125       // 32-node output tiles for tile_g1
#define NBUCK 391         // 256-node buckets: dst>>8
#define NBLK_A 512        // blocks in count/place passes
#define GCNT_N (NBUCK * NBLK_A)            // 200192
#define NCHUNK ((GCNT_N + 255) / 256)      // 782
#define NTILE_T (N_NODES / 32)             // transform tiles
#define TROW 72           // staged row stride in bf16 elems (144B)

typedef __attribute__((ext_vector_type(8))) short short8;
typedef __attribute__((ext_vector_type(16))) float f32x16;
union Pack8 { uint4 u; short8 s; };

__device__ __forceinline__ unsigned f2bf(float f) {  // RNE float->bf16 bits
  unsigned u = __float_as_uint(f);
  return (u + 0x7fffu + ((u >> 16) & 1u)) >> 16;
}
#define BF_LO(u) __uint_as_float(((unsigned)(u)) << 16)
#define BF_HI(u) __uint_as_float(((unsigned)(u)) & 0xffff0000u)

// ---------- counting-sort to 256-node buckets, then per-node in passD ------

__global__ __launch_bounds__(256) void passA_count(const int* __restrict__ dst,
                                                   int* __restrict__ gcnt,
                                                   int nE, int ec) {
  __shared__ int cnt[NBUCK];
  int t = threadIdx.x, blk = blockIdx.x;
  for (int i = t; i < NBUCK; i += 256) cnt[i] = 0;
  __syncthreads();
  int e0 = blk * ec, e1 = min(e0 + ec, nE);
  for (int e = e0 + t; e < e1; e += 256) atomicAdd(&cnt[dst[e] >> 8], 1);
  __syncthreads();
  for (int b = t; b < NBUCK; b += 256) gcnt[b * NBLK_A + blk] = cnt[b];
}

__global__ void gscan_p1(const int* __restrict__ g, int* __restrict__ csum) {
  int t = threadIdx.x, b = blockIdx.x;
  int i = b * 256 + t;
  int v = (i < GCNT_N) ? g[i] : 0;
  for (int off = 32; off; off >>= 1) v += __shfl_down(v, off);
  __shared__ int ws4[4];
  if ((t & 63) == 0) ws4[t >> 6] = v;
  __syncthreads();
  if (t == 0) csum[b] = ws4[0] + ws4[1] + ws4[2] + ws4[3];
}

__global__ void gscan_p2(int* __restrict__ csum, int nB) {
  __shared__ int s[1024];
  int t = threadIdx.x;
  int orig = (t < nB) ? csum[t] : 0;
  s[t] = orig;
  __syncthreads();
  for (int off = 1; off < 1024; off <<= 1) {
    int v = (t >= off) ? s[t - off] : 0;
    __syncthreads();
    s[t] += v;
    __syncthreads();
  }
  if (t < nB) csum[t] = s[t] - orig;  // exclusive block offsets
}

__global__ void gscan_p3(int* __restrict__ g, const int* __restrict__ csum) {
  __shared__ int s[256];
  int t = threadIdx.x, b = blockIdx.x;
  int i = b * 256 + t;
  int d = (i < GCNT_N) ? g[i] : 0;
  s[t] = d;
  __syncthreads();
  for (int off = 1; off < 256; off <<= 1) {
    int v = (t >= off) ? s[t - off] : 0;
    __syncthreads();
    s[t] += v;
    __syncthreads();
  }
  if (i < GCNT_N) g[i] = s[t] - d + csum[b];  // exclusive
}

__global__ __launch_bounds__(256) void passC_place(const int* __restrict__ src,
                                                   const int* __restrict__ dst,
                                                   const int* __restrict__ S,
                                                   uint2* __restrict__ pairs,
                                                   int nE, int ec) {
  __shared__ int cur[NBUCK];
  int t = threadIdx.x, blk = blockIdx.x;
  for (int b = t; b < NBUCK; b += 256) cur[b] = S[b * NBLK_A + blk];
  __syncthreads();
  int e0 = blk * ec, e1 = min(e0 + ec, nE);
  for (int e = e0 + t; e < e1; e += 256) {
    int d = dst[e];
    int p = atomicAdd(&cur[d >> 8], 1);
    pairs[p] = make_uint2((unsigned)d, (unsigned)src[e]);
  }
}

// Pass D: per 256-node bucket -> rowstart/deg + fully node-sorted pairs (srt).
__global__ __launch_bounds__(256) void passD_csr(const uint2* __restrict__ pairs,
                                                 const int* __restrict__ S,
                                                 int* __restrict__ rowstart,
                                                 int* __restrict__ degI,
                                                 uint2* __restrict__ srt,
                                                 int nE) {
  __shared__ int lh[256];
  __shared__ int sc[256];
  __shared__ int cur[256];
  int t = threadIdx.x, b = blockIdx.x;
  int base = S[b * NBLK_A];
  int end = (b == NBUCK - 1) ? nE : S[(b + 1) * NBLK_A];
  lh[t] = 0;
  __syncthreads();
  for (int p = base + t; p < end; p += 256) atomicAdd(&lh[pairs[p].x & 255], 1);
  __syncthreads();
  int d = lh[t];
  sc[t] = d;
  __syncthreads();
  for (int off = 1; off < 256; off <<= 1) {
    int v = (t >= off) ? sc[t - off] : 0;
    __syncthreads();
    sc[t] += v;
    __syncthreads();
  }
  int ex = sc[t] - d;
  int node = b * 256 + t;
  if (node < N_NODES) {
    rowstart[node] = base + ex;
    degI[node] = d;
  }
  cur[t] = base + ex;
  __syncthreads();
  for (int p = base + t; p < end; p += 256) {
    uint2 e = pairs[p];
    int slot = atomicAdd(&cur[e.x & 255], 1);
    srt[slot] = e;
  }
}

// ---------- prep: fold classifier (A2,B2,bf) + wcat bf16 staging ----------
__global__ __launch_bounds__(256) void prep_kernel(
    const float* __restrict__ Wc, const float* __restrict__ Wl2,
    const float* __restrict__ Wr2, const float* __restrict__ bl2,
    const float* __restrict__ bc, const float* __restrict__ Wl1,
    const float* __restrict__ Wr1, float* __restrict__ A2,
    float* __restrict__ B2, float* __restrict__ bfv,
    unsigned short* __restrict__ wcat) {
  int t = threadIdx.x;
  for (int i = t; i < 8192; i += 256)
    wcat[i] = (unsigned short)f2bf((i < 4096) ? Wl1[i] : Wr1[i - 4096]);
  if (t < 128) {
    int c = t >> 6, k = t & 63;
    float sa = 0.f, sb = 0.f;
    for (int j = 0; j < 64; ++j) {
      float w = Wc[c * 64 + j];
      sa = fmaf(w, Wl2[j * 64 + k], sa);
      sb = fmaf(w, Wr2[j * 64 + k], sb);
    }
    A2[c * 64 + k] = sa;
    B2[c * 64 + k] = sb;
  }
  if (t < 2) {
    float s = bc[t];
    for (int j = 0; j < 64; ++j) s = fmaf(Wc[t * 64 + j], bl2[j], s);
    bfv[t] = s;
  }
}

// ---------- transform_mfma: t1 = x@Wl1^T (bf16), r1b = x@Wr1^T+b (bf16) ----
__global__ __launch_bounds__(256) void transform_mfma(
    const float* __restrict__ x, const unsigned short* __restrict__ wcat,
    const float* __restrict__ bl, unsigned short* __restrict__ t1,
    unsigned short* __restrict__ r1b) {
  int tid = threadIdx.x, lane = tid & 63;
  int l31 = lane & 31, hi = lane >> 5;

  short8 af[4][4];
#pragma unroll
  for (int jt = 0; jt < 4; ++jt)
#pragma unroll
    for (int kk = 0; kk < 4; ++kk)
      af[jt][kk] = *(const short8*)(wcat + (jt * 32 + l31) * 64 + kk * 16 + 8 * hi);

  const f32x16 Z = {0.f, 0.f, 0.f, 0.f, 0.f, 0.f, 0.f, 0.f,
                    0.f, 0.f, 0.f, 0.f, 0.f, 0.f, 0.f, 0.f};
  const float4* x4 = (const float4*)x;

  int gw = (blockIdx.x * 256 + tid) >> 6;
  int nW = (gridDim.x * 256) >> 6;

  for (int tile = gw; tile < NTILE_T; tile += nW) {
    int node = tile * 32 + l31;
    f32x16 acc[4] = {Z, Z, Z, Z};
#pragma unroll
    for (int kk = 0; kk < 4; ++kk) {
      float4 fa = x4[(size_t)node * 16 + kk * 4 + 2 * hi];
      float4 fb = x4[(size_t)node * 16 + kk * 4 + 2 * hi + 1];
      Pack8 pk;
      pk.u.x = f2bf(fa.x) | (f2bf(fa.y) << 16);
      pk.u.y = f2bf(fa.z) | (f2bf(fa.w) << 16);
      pk.u.z = f2bf(fb.x) | (f2bf(fb.y) << 16);
      pk.u.w = f2bf(fb.z) | (f2bf(fb.w) << 16);
      acc[0] = __builtin_amdgcn_mfma_f32_32x32x16_bf16(af[0][kk], pk.s, acc[0], 0, 0, 0);
      acc[1] = __builtin_amdgcn_mfma_f32_32x32x16_bf16(af[1][kk], pk.s, acc[1], 0, 0, 0);
      acc[2] = __builtin_amdgcn_mfma_f32_32x32x16_bf16(af[2][kk], pk.s, acc[2], 0, 0, 0);
      acc[3] = __builtin_amdgcn_mfma_f32_32x32x16_bf16(af[3][kk], pk.s, acc[3], 0, 0, 0);
    }
#pragma unroll
    for (int jt = 0; jt < 2; ++jt)
#pragma unroll
      for (int rg = 0; rg < 4; ++rg) {
        int j0 = jt * 32 + 8 * rg + 4 * hi;
        uint2 p;
        p.x = f2bf(acc[jt][4 * rg + 0]) | (f2bf(acc[jt][4 * rg + 1]) << 16);
        p.y = f2bf(acc[jt][4 * rg + 2]) | (f2bf(acc[jt][4 * rg + 3]) << 16);
        *(uint2*)(t1 + (size_t)node * 64 + j0) = p;
      }
#pragma unroll
    for (int jt = 2; jt < 4; ++jt)
#pragma unroll
      for (int rg = 0; rg < 4; ++rg) {
        int j0 = (jt - 2) * 32 + 8 * rg + 4 * hi;
        float4 bv = ((const float4*)bl)[j0 >> 2];
        uint2 p;
        p.x = f2bf(acc[jt][4 * rg + 0] + bv.x) |
              (f2bf(acc[jt][4 * rg + 1] + bv.y) << 16);
        p.y = f2bf(acc[jt][4 * rg + 2] + bv.z) |
              (f2bf(acc[jt][4 * rg + 3] + bv.w) << 16);
        *(uint2*)(r1b + (size_t)node * 64 + j0) = p;
      }
  }
}

// ---------- tile_g1 v2: MFMA indicator-gather, 4 waves per tile ----------
// One BLOCK per 32-dst tile; the tile's edge range splits into 4 contiguous
// quarter-ranges (one per wave). Each wave runs the pipelined 16-edge-group
// loop (stage rows to LDS, transpose-read as MFMA A, one-hot B, D += AxB).
// Partial accumulators reduced across waves via LDS (staging bufs reused).
__global__ __launch_bounds__(256) void tile_g1(
    const uint2* __restrict__ srt, const int* __restrict__ rowstart,
    const unsigned short* __restrict__ t1,
    const unsigned short* __restrict__ r1b, const float* __restrict__ A2,
    const float* __restrict__ B2, float2* __restrict__ g2,
    float2* __restrict__ s2, int nE) {
  __shared__ float pAB[4][64];
  __shared__ unsigned short stg[4][2][16 * TROW];
  __shared__ int ideg[4][64];
  int t = threadIdx.x, lane = t & 63, w = t >> 6;
  pAB[t >> 6][t & 63] = (t < 128) ? A2[t] : B2[t - 128];
  __syncthreads();

  int tile = blockIdx.x;
  int base = rowstart[tile * 32];
  int end = (tile == NTILES - 1) ? nE : rowstart[(tile + 1) * 32];
  int l31 = lane & 31, hi = lane >> 5;
  int o = lane >> 3, j8 = lane & 7;
  unsigned short* stA = &stg[w][0][0];
  unsigned short* stB = &stg[w][1][0];

  // quarter-range for this wave (16-edge-group aligned)
  int ngAll = (end > base) ? ((end - base + 15) >> 4) : 0;
  int gper = (ngAll + 3) >> 2;
  int wbase = base + min(w * gper, ngAll) * 16;
  int wend = min(base + min((w + 1) * gper, ngAll) * 16, end);

  const f32x16 Z = {0.f, 0.f, 0.f, 0.f, 0.f, 0.f, 0.f, 0.f,
                    0.f, 0.f, 0.f, 0.f, 0.f, 0.f, 0.f, 0.f};
  f32x16 acc0 = Z, acc1 = Z;
  int degc = 0;
  int ng = (wend > wbase) ? ((wend - wbase + 15) >> 4) : 0;

  uint2 prA = make_uint2(0u, 0u), prB = make_uint2(0u, 0u);
  int cntA = 0, cntB = 0;
  uint4 vA0 = make_uint4(0, 0, 0, 0), vA1 = vA0, vB0 = vA0, vB1 = vA0;
  if (ng > 0) {
    prA = srt[min(wbase + (lane & 15), nE - 1)];
    cntA = min(wend - wbase, 16);
    int s0 = __shfl((int)prA.y, o), s1 = __shfl((int)prA.y, 8 + o);
    vA0 = *(const uint4*)(t1 + (size_t)((o < cntA) ? s0 : 0) * 64 + j8 * 8);
    vA1 = *(const uint4*)(t1 + (size_t)((8 + o < cntA) ? s1 : 0) * 64 + j8 * 8);
  }
  if (ng > 1) {
    int nb = wbase + 16;
    prB = srt[min(nb + (lane & 15), nE - 1)];
    cntB = min(wend - nb, 16);
    int s0 = __shfl((int)prB.y, o), s1 = __shfl((int)prB.y, 8 + o);
    vB0 = *(const uint4*)(t1 + (size_t)((o < cntB) ? s0 : 0) * 64 + j8 * 8);
    vB1 = *(const uint4*)(t1 + (size_t)((8 + o < cntB) ? s1 : 0) * 64 + j8 * 8);
  }

  for (int gg = 0; gg < ng; gg += 2) {
    bool hasB = (gg + 1 < ng);
    *(uint4*)(stA + o * TROW + j8 * 8) = vA0;
    *(uint4*)(stA + (8 + o) * TROW + j8 * 8) = vA1;
    if (hasB) {
      *(uint4*)(stB + o * TROW + j8 * 8) = vB0;
      *(uint4*)(stB + (8 + o) * TROW + j8 * 8) = vB1;
    }
    unsigned amA[8], amB[8];
#pragma unroll
    for (int m = 0; m < 8; ++m) {
      int e = 8 * hi + m;
      int dv = __shfl((int)prA.x, e);
      bool ok = (e < cntA) && ((dv & 31) == l31);
      amA[m] = ok ? 0x3F80u : 0u;
      degc += (amA[m] >> 7) & 1;
    }
    if (hasB) {
#pragma unroll
      for (int m = 0; m < 8; ++m) {
        int e = 8 * hi + m;
        int dv = __shfl((int)prB.x, e);
        bool ok = (e < cntB) && ((dv & 31) == l31);
        amB[m] = ok ? 0x3F80u : 0u;
        degc += (amB[m] >> 7) & 1;
      }
    }
    if (gg + 2 < ng) {
      int nb = wbase + (gg + 2) * 16;
      prA = srt[min(nb + (lane & 15), nE - 1)];
      cntA = min(wend - nb, 16);
      int s0 = __shfl((int)prA.y, o), s1 = __shfl((int)prA.y, 8 + o);
      vA0 = *(const uint4*)(t1 + (size_t)((o < cntA) ? s0 : 0) * 64 + j8 * 8);
      vA1 = *(const uint4*)(t1 + (size_t)((8 + o < cntA) ? s1 : 0) * 64 + j8 * 8);
    }
    if (gg + 3 < ng) {
      int nb = wbase + (gg + 3) * 16;
      prB = srt[min(nb + (lane & 15), nE - 1)];
      cntB = min(wend - nb, 16);
      int s0 = __shfl((int)prB.y, o), s1 = __shfl((int)prB.y, 8 + o);
      vB0 = *(const uint4*)(t1 + (size_t)((o < cntB) ? s0 : 0) * 64 + j8 * 8);
      vB1 = *(const uint4*)(t1 + (size_t)((8 + o < cntB) ? s1 : 0) * 64 + j8 * 8);
    }
    {
      Pack8 I;
      I.u.x = amA[0] | (amA[1] << 16);
      I.u.y = amA[2] | (amA[3] << 16);
      I.u.z = amA[4] | (amA[5] << 16);
      I.u.w = amA[6] | (amA[7] << 16);
      unsigned short b0[8], b1[8];
#pragma unroll
      for (int m = 0; m < 8; ++m) {
        b0[m] = stA[(8 * hi + m) * TROW + l31];
        b1[m] = stA[(8 * hi + m) * TROW + 32 + l31];
      }
      Pack8 F0, F1;
      F0.u.x = b0[0] | ((unsigned)b0[1] << 16);
      F0.u.y = b0[2] | ((unsigned)b0[3] << 16);
      F0.u.z = b0[4] | ((unsigned)b0[5] << 16);
      F0.u.w = b0[6] | ((unsigned)b0[7] << 16);
      F1.u.x = b1[0] | ((unsigned)b1[1] << 16);
      F1.u.y = b1[2] | ((unsigned)b1[3] << 16);
      F1.u.z = b1[4] | ((unsigned)b1[5] << 16);
      F1.u.w = b1[6] | ((unsigned)b1[7] << 16);
      acc0 = __builtin_amdgcn_mfma_f32_32x32x16_bf16(F0.s, I.s, acc0, 0, 0, 0);
      acc1 = __builtin_amdgcn_mfma_f32_32x32x16_bf16(F1.s, I.s, acc1, 0, 0, 0);
    }
    if (hasB) {
      Pack8 I;
      I.u.x = amB[0] | (amB[1] << 16);
      I.u.y = amB[2] | (amB[3] << 16);
      I.u.z = amB[4] | (amB[5] << 16);
      I.u.w = amB[6] | (amB[7] << 16);
      unsigned short b0[8], b1[8];
#pragma unroll
      for (int m = 0; m < 8; ++m) {
        b0[m] = stB[(8 * hi + m) * TROW + l31];
        b1[m] = stB[(8 * hi + m) * TROW + 32 + l31];
      }
      Pack8 F0, F1;
      F0.u.x = b0[0] | ((unsigned)b0[1] << 16);
      F0.u.y = b0[2] | ((unsigned)b0[3] << 16);
      F0.u.z = b0[4] | ((unsigned)b0[5] << 16);
      F0.u.w = b0[6] | ((unsigned)b0[7] << 16);
      F1.u.x = b1[0] | ((unsigned)b1[1] << 16);
      F1.u.y = b1[2] | ((unsigned)b1[3] << 16);
      F1.u.z = b1[4] | ((unsigned)b1[5] << 16);
      F1.u.w = b1[6] | ((unsigned)b1[7] << 16);
      acc0 = __builtin_amdgcn_mfma_f32_32x32x16_bf16(F0.s, I.s, acc0, 0, 0, 0);
      acc1 = __builtin_amdgcn_mfma_f32_32x32x16_bf16(F1.s, I.s, acc1, 0, 0, 0);
    }
  }

  // ---- cross-wave reduction (reuse stg as f32 buffer; bank-safe layout) ----
  ideg[w][lane] = degc;
  __syncthreads();
  float* red = (float*)&stg[0][0][0];  // 64 lanes x 32 f32 = 8 KB
  for (int r = 1; r < 4; ++r) {
    if (w == r) {
#pragma unroll
      for (int i = 0; i < 16; ++i) {
        red[i * 64 + lane] = acc0[i];
        red[(16 + i) * 64 + lane] = acc1[i];
      }
    }
    __syncthreads();
    if (w == 0) {
#pragma unroll
      for (int i = 0; i < 16; ++i) {
        acc0[i] += red[i * 64 + lane];
        acc1[i] += red[(16 + i) * 64 + lane];
      }
    }
    __syncthreads();
  }

  if (w == 0) {
    int dtot = ideg[0][lane] + ideg[1][lane] + ideg[2][lane] + ideg[3][lane];
    float degf = (float)(dtot + __shfl_xor(dtot, 32));
    float inv = 1.f / fmaxf(degf, 1.f);
    int node = tile * 32 + l31;
    float d0 = 0.f, d1 = 0.f, d2 = 0.f, d3 = 0.f;
#pragma unroll
    for (int fb = 0; fb < 2; ++fb) {
#pragma unroll
      for (int q4 = 0; q4 < 4; ++q4) {
        int f0 = fb * 32 + q4 * 8 + 4 * hi;
        uint2 rv = *(const uint2*)(r1b + (size_t)node * 64 + f0);
        float bias[4] = {BF_LO(rv.x), BF_HI(rv.x), BF_LO(rv.y), BF_HI(rv.y)};
#pragma unroll
        for (int j = 0; j < 4; ++j) {
          float a = fb ? acc1[q4 * 4 + j] : acc0[q4 * 4 + j];
          float hv = fmaxf(fmaf(a, inv, bias[j]), 0.f);
          int f = f0 + j;
          d0 = fmaf(hv, pAB[0][f], d0);
          d1 = fmaf(hv, pAB[1][f], d1);
          d2 = fmaf(hv, pAB[2][f], d2);
          d3 = fmaf(hv, pAB[3][f], d3);
        }
      }
    }
    d0 += __shfl_xor(d0, 32);
    d1 += __shfl_xor(d1, 32);
    d2 += __shfl_xor(d2, 32);
    d3 += __shfl_xor(d3, 32);
    if (hi == 0) {
      g2[node] = make_float2(d0, d1);
      s2[node] = make_float2(d2, d3);
    }
  }
}

// ---------- gather2: out[n] = mean_j(g2[j]) + s2[n] + bf ----------
__global__ __launch_bounds__(256) void gather2_kernel(
    const int* __restrict__ rowstart, const int* __restrict__ degI,
    const uint2* __restrict__ srt, const float2* __restrict__ g2,
    const float2* __restrict__ s2, const float* __restrict__ bfv,
    float* __restrict__ out, int nE) {
  int tid = threadIdx.x, lane = tid & 63;
  int q = lane >> 4, l16 = lane & 15;
  float bf0 = bfv[0], bf1 = bfv[1];
  int gq = ((blockIdx.x * 256 + tid) >> 6) * 4 + q;
  int strideN = ((gridDim.x * 256) >> 6) * 4;
  for (int n = gq; n < N_NODES; n += strideN) {
    int rs = rowstart[n], dg = degI[n];
    float s0 = 0.f, s1 = 0.f;
    for (int base = 0; base < dg; base += 16) {
      int e = base + l16;
      int a = (int)srt[min(rs + ((e < dg) ? e : 0), nE - 1)].y;
      float2 v = g2[a];
      float m = (e < dg) ? 1.f : 0.f;
      s0 = fmaf(v.x, m, s0);
      s1 = fmaf(v.y, m, s1);
    }
    s0 += __shfl_xor(s0, 1); s0 += __shfl_xor(s0, 2);
    s0 += __shfl_xor(s0, 4); s0 += __shfl_xor(s0, 8);
    s1 += __shfl_xor(s1, 1); s1 += __shfl_xor(s1, 2);
    s1 += __shfl_xor(s1, 4); s1 += __shfl_xor(s1, 8);
    if (l16 == 0) {
      float inv = 1.f / (float)max(dg, 1);
      float2 sv = s2[n];
      out[(size_t)n * 2 + 0] = fmaf(s0, inv, sv.x) + bf0;
      out[(size_t)n * 2 + 1] = fmaf(s1, inv, sv.y) + bf1;
    }
  }
}

extern "C" void kernel_launch(void* const* d_in, const int* in_sizes, int n_in,
                              void* d_out, int out_size, void* d_ws,
                              size_t ws_size, hipStream_t stream) {
  const float* x   = (const float*)d_in[0];
  const int*   ei  = (const int*)d_in[1];
  const float* Wl1 = (const float*)d_in[2];
  const float* bl1 = (const float*)d_in[3];
  const float* Wr1 = (const float*)d_in[4];
  const float* Wl2 = (const float*)d_in[5];
  const float* bl2 = (const float*)d_in[6];
  const float* Wr2 = (const float*)d_in[7];
  const float* Wc  = (const float*)d_in[8];
  const float* bc  = (const float*)d_in[9];
  float* out = (float*)d_out;

  int nE = in_sizes[1] / 2;
  const int* src = ei;
  const int* dst = ei + nE;

  // Workspace (~40 MB): t1 bf16[N*64] (aliases pairs uint2[E]; pairs dead
  // before transform writes t1) | srt uint2[E] | r1b bf16[N*64] | g2,s2 |
  // A2/B2/bf | wcat | degI,rowstart [N] | gcnt[200k] | csum[1024]
  unsigned short* t1 = (unsigned short*)d_ws;
  uint2* pairs = (uint2*)d_ws;  // alias with t1
  uint2* srt = (uint2*)(t1 + (size_t)N_NODES * D);
  unsigned short* r1b = (unsigned short*)(srt + nE);
  float2* g2 = (float2*)(r1b + (size_t)N_NODES * D);
  float2* s2 = g2 + N_NODES;
  float* A2 = (float*)(s2 + N_NODES);
  float* B2 = A2 + 128;
  float* bfv = B2 + 128;
  unsigned short* wcat = (unsigned short*)(bfv + 4);
  int* degI = (int*)(wcat + 8192);
  int* rowstart = degI + N_NODES;
  int* gcnt = rowstart + N_NODES;
  int* csum = gcnt + GCNT_N;

  int ec = (nE + NBLK_A - 1) / NBLK_A;

  passA_count<<<NBLK_A, 256, 0, stream>>>(dst, gcnt, nE, ec);
  gscan_p1<<<NCHUNK, 256, 0, stream>>>(gcnt, csum);
  gscan_p2<<<1, 1024, 0, stream>>>(csum, NCHUNK);
  gscan_p3<<<NCHUNK, 256, 0, stream>>>(gcnt, csum);
  passC_place<<<NBLK_A, 256, 0, stream>>>(src, dst, gcnt, pairs, nE, ec);
  passD_csr<<<NBUCK, 256, 0, stream>>>(pairs, gcnt, rowstart, degI, srt, nE);

  prep_kernel<<<1, 256, 0, stream>>>(Wc, Wl2, Wr2, bl2, bc, Wl1, Wr1, A2, B2,
                                     bfv, wcat);
  transform_mfma<<<512, 256, 0, stream>>>(x, wcat, bl1, t1, r1b);

  tile_g1<<<NTILES, 256, 0, stream>>>(srt, rowstart, t1, r1b, A2, B2, g2, s2,
                                      nE);
  gather2_kernel<<<512, 256, 0, stream>>>(rowstart, degI, srt, g2, s2, bfv,
                                          out, nE);
}

// Round 15
// 131.149 us; speedup vs baseline: 4.8166x; 1.0939x over previous
//
#include <hip/hip_runtime.h>

#define N_NODES 100000
#define D 64
#define NTILES 3125       // 32-node output tiles for tile_g1
#define NBUCK 391         // 256-node buckets: dst>>8
#define NBLK_A 256        // blocks in count/place passes
#define GCNT_N (NBUCK * NBLK_A)            // 100096
#define NCHUNK ((GCNT_N + 255) / 256)      // 391
#define NTILE_T (N_NODES / 32)             // transform tiles
#define TROW 72           // staged row stride in bf16 elems (144B)
#define TBLK 512          // transform blocks inside fused kernel

typedef __attribute__((ext_vector_type(8))) short short8;
typedef __attribute__((ext_vector_type(16))) float f32x16;
union Pack8 { uint4 u; short8 s; };

__device__ __forceinline__ unsigned f2bf(float f) {  // RNE float->bf16 bits
  unsigned u = __float_as_uint(f);
  return (u + 0x7fffu + ((u >> 16) & 1u)) >> 16;
}
#define BF_LO(u) __uint_as_float(((unsigned)(u)) << 16)
#define BF_HI(u) __uint_as_float(((unsigned)(u)) & 0xffff0000u)

// ---------- counting-sort to 256-node buckets ----------

__global__ __launch_bounds__(256) void passA_count(const int* __restrict__ dst,
                                                   int* __restrict__ gcnt,
                                                   int nE, int ec) {
  __shared__ int cnt[NBUCK];
  int t = threadIdx.x, blk = blockIdx.x;
  for (int i = t; i < NBUCK; i += 256) cnt[i] = 0;
  __syncthreads();
  int e0 = blk * ec, e1 = min(e0 + ec, nE);
  for (int e = e0 + t; e < e1; e += 256) atomicAdd(&cnt[dst[e] >> 8], 1);
  __syncthreads();
  for (int b = t; b < NBUCK; b += 256) gcnt[b * NBLK_A + blk] = cnt[b];
}

__global__ void gscan_p1(const int* __restrict__ g, int* __restrict__ csum) {
  int t = threadIdx.x, b = blockIdx.x;
  int i = b * 256 + t;
  int v = (i < GCNT_N) ? g[i] : 0;
  for (int off = 32; off; off >>= 1) v += __shfl_down(v, off);
  __shared__ int ws4[4];
  if ((t & 63) == 0) ws4[t >> 6] = v;
  __syncthreads();
  if (t == 0) csum[b] = ws4[0] + ws4[1] + ws4[2] + ws4[3];
}

__global__ void gscan_p2(int* __restrict__ csum, int nB) {
  __shared__ int s[1024];
  int t = threadIdx.x;
  int orig = (t < nB) ? csum[t] : 0;
  s[t] = orig;
  __syncthreads();
  for (int off = 1; off < 1024; off <<= 1) {
    int v = (t >= off) ? s[t - off] : 0;
    __syncthreads();
    s[t] += v;
    __syncthreads();
  }
  if (t < nB) csum[t] = s[t] - orig;  // exclusive block offsets
}

__global__ void gscan_p3(int* __restrict__ g, const int* __restrict__ csum) {
  __shared__ int s[256];
  int t = threadIdx.x, b = blockIdx.x;
  int i = b * 256 + t;
  int d = (i < GCNT_N) ? g[i] : 0;
  s[t] = d;
  __syncthreads();
  for (int off = 1; off < 256; off <<= 1) {
    int v = (t >= off) ? s[t - off] : 0;
    __syncthreads();
    s[t] += v;
    __syncthreads();
  }
  if (i < GCNT_N) g[i] = s[t] - d + csum[b];  // exclusive
}

// ---------- passC (blocks 0..NBLK_A-1) + prep (block NBLK_A) fused ----------
__global__ __launch_bounds__(256) void passC_prep(
    const int* __restrict__ src, const int* __restrict__ dst,
    const int* __restrict__ S, uint2* __restrict__ pairs, int nE, int ec,
    const float* __restrict__ Wc, const float* __restrict__ Wl2,
    const float* __restrict__ Wr2, const float* __restrict__ bl2,
    const float* __restrict__ bc, const float* __restrict__ Wl1,
    const float* __restrict__ Wr1, float* __restrict__ A2,
    float* __restrict__ B2, float* __restrict__ bfv,
    unsigned short* __restrict__ wcat) {
  __shared__ int cur[NBUCK];
  int t = threadIdx.x, blk = blockIdx.x;
  if (blk < NBLK_A) {
    for (int b = t; b < NBUCK; b += 256) cur[b] = S[b * NBLK_A + blk];
    __syncthreads();
    int e0 = blk * ec, e1 = min(e0 + ec, nE);
    for (int e = e0 + t; e < e1; e += 256) {
      int d = dst[e];
      int p = atomicAdd(&cur[d >> 8], 1);
      pairs[p] = make_uint2((unsigned)d, (unsigned)src[e]);
    }
  } else {
    for (int i = t; i < 8192; i += 256)
      wcat[i] = (unsigned short)f2bf((i < 4096) ? Wl1[i] : Wr1[i - 4096]);
    if (t < 128) {
      int c = t >> 6, k = t & 63;
      float sa = 0.f, sb = 0.f;
      for (int j = 0; j < 64; ++j) {
        float w = Wc[c * 64 + j];
        sa = fmaf(w, Wl2[j * 64 + k], sa);
        sb = fmaf(w, Wr2[j * 64 + k], sb);
      }
      A2[c * 64 + k] = sa;
      B2[c * 64 + k] = sb;
    }
    if (t < 2) {
      float s = bc[t];
      for (int j = 0; j < 64; ++j) s = fmaf(Wc[t * 64 + j], bl2[j], s);
      bfv[t] = s;
    }
  }
}

// ---------- fused: passD (blocks 0..NBUCK-1) + transform (rest) ----------
// Independent work co-scheduled in one dispatch: passD is memory-bound
// (pairs re-sort), transform is MFMA-bound; overlapping them takes ~max
// instead of sum.
__global__ __launch_bounds__(256) void passD_transform(
    const uint2* __restrict__ pairs, const int* __restrict__ S,
    int* __restrict__ rowstart, int* __restrict__ degI,
    uint2* __restrict__ srt, int nE,
    const float* __restrict__ x, const unsigned short* __restrict__ wcat,
    const float* __restrict__ bl, unsigned short* __restrict__ t1,
    unsigned short* __restrict__ r1b) {
  __shared__ int lh[256];
  __shared__ int sc[256];
  __shared__ int cur[256];
  int t = threadIdx.x;
  if (blockIdx.x < NBUCK) {
    int b = blockIdx.x;
    int base = S[b * NBLK_A];
    int end = (b == NBUCK - 1) ? nE : S[(b + 1) * NBLK_A];
    lh[t] = 0;
    __syncthreads();
    for (int p = base + t; p < end; p += 256) atomicAdd(&lh[pairs[p].x & 255], 1);
    __syncthreads();
    int d = lh[t];
    sc[t] = d;
    __syncthreads();
    for (int off = 1; off < 256; off <<= 1) {
      int v = (t >= off) ? sc[t - off] : 0;
      __syncthreads();
      sc[t] += v;
      __syncthreads();
    }
    int ex = sc[t] - d;
    int node = b * 256 + t;
    if (node < N_NODES) {
      rowstart[node] = base + ex;
      degI[node] = d;
    }
    cur[t] = base + ex;
    __syncthreads();
    for (int p = base + t; p < end; p += 256) {
      uint2 e = pairs[p];
      int slot = atomicAdd(&cur[e.x & 255], 1);
      srt[slot] = e;
    }
  } else {
    int lane = t & 63;
    int l31 = lane & 31, hi = lane >> 5;

    short8 af[4][4];
#pragma unroll
    for (int jt = 0; jt < 4; ++jt)
#pragma unroll
      for (int kk = 0; kk < 4; ++kk)
        af[jt][kk] =
            *(const short8*)(wcat + (jt * 32 + l31) * 64 + kk * 16 + 8 * hi);

    const f32x16 Z = {0.f, 0.f, 0.f, 0.f, 0.f, 0.f, 0.f, 0.f,
                      0.f, 0.f, 0.f, 0.f, 0.f, 0.f, 0.f, 0.f};
    const float4* x4 = (const float4*)x;

    int gw = ((blockIdx.x - NBUCK) * 256 + t) >> 6;
    int nW = (TBLK * 256) >> 6;

    for (int tile = gw; tile < NTILE_T; tile += nW) {
      int node = tile * 32 + l31;
      f32x16 acc[4] = {Z, Z, Z, Z};
#pragma unroll
      for (int kk = 0; kk < 4; ++kk) {
        float4 fa = x4[(size_t)node * 16 + kk * 4 + 2 * hi];
        float4 fb = x4[(size_t)node * 16 + kk * 4 + 2 * hi + 1];
        Pack8 pk;
        pk.u.x = f2bf(fa.x) | (f2bf(fa.y) << 16);
        pk.u.y = f2bf(fa.z) | (f2bf(fa.w) << 16);
        pk.u.z = f2bf(fb.x) | (f2bf(fb.y) << 16);
        pk.u.w = f2bf(fb.z) | (f2bf(fb.w) << 16);
        acc[0] = __builtin_amdgcn_mfma_f32_32x32x16_bf16(af[0][kk], pk.s, acc[0], 0, 0, 0);
        acc[1] = __builtin_amdgcn_mfma_f32_32x32x16_bf16(af[1][kk], pk.s, acc[1], 0, 0, 0);
        acc[2] = __builtin_amdgcn_mfma_f32_32x32x16_bf16(af[2][kk], pk.s, acc[2], 0, 0, 0);
        acc[3] = __builtin_amdgcn_mfma_f32_32x32x16_bf16(af[3][kk], pk.s, acc[3], 0, 0, 0);
      }
#pragma unroll
      for (int jt = 0; jt < 2; ++jt)
#pragma unroll
        for (int rg = 0; rg < 4; ++rg) {
          int j0 = jt * 32 + 8 * rg + 4 * hi;
          uint2 p;
          p.x = f2bf(acc[jt][4 * rg + 0]) | (f2bf(acc[jt][4 * rg + 1]) << 16);
          p.y = f2bf(acc[jt][4 * rg + 2]) | (f2bf(acc[jt][4 * rg + 3]) << 16);
          *(uint2*)(t1 + (size_t)node * 64 + j0) = p;
        }
#pragma unroll
      for (int jt = 2; jt < 4; ++jt)
#pragma unroll
        for (int rg = 0; rg < 4; ++rg) {
          int j0 = (jt - 2) * 32 + 8 * rg + 4 * hi;
          float4 bv = ((const float4*)bl)[j0 >> 2];
          uint2 p;
          p.x = f2bf(acc[jt][4 * rg + 0] + bv.x) |
                (f2bf(acc[jt][4 * rg + 1] + bv.y) << 16);
          p.y = f2bf(acc[jt][4 * rg + 2] + bv.z) |
                (f2bf(acc[jt][4 * rg + 3] + bv.w) << 16);
          *(uint2*)(r1b + (size_t)node * 64 + j0) = p;
        }
    }
  }
}

// ---------- tile_g1 v2: MFMA indicator-gather, 4 waves per tile ----------
__global__ __launch_bounds__(256) void tile_g1(
    const uint2* __restrict__ srt, const int* __restrict__ rowstart,
    const unsigned short* __restrict__ t1,
    const unsigned short* __restrict__ r1b, const float* __restrict__ A2,
    const float* __restrict__ B2, float2* __restrict__ g2,
    float2* __restrict__ s2, int nE) {
  __shared__ float pAB[4][64];
  __shared__ unsigned short stg[4][2][16 * TROW];
  __shared__ int ideg[4][64];
  int t = threadIdx.x, lane = t & 63, w = t >> 6;
  pAB[t >> 6][t & 63] = (t < 128) ? A2[t] : B2[t - 128];
  __syncthreads();

  int tile = blockIdx.x;
  int base = rowstart[tile * 32];
  int end = (tile == NTILES - 1) ? nE : rowstart[(tile + 1) * 32];
  int l31 = lane & 31, hi = lane >> 5;
  int o = lane >> 3, j8 = lane & 7;
  unsigned short* stA = &stg[w][0][0];
  unsigned short* stB = &stg[w][1][0];

  int ngAll = (end > base) ? ((end - base + 15) >> 4) : 0;
  int gper = (ngAll + 3) >> 2;
  int wbase = base + min(w * gper, ngAll) * 16;
  int wend = min(base + min((w + 1) * gper, ngAll) * 16, end);

  const f32x16 Z = {0.f, 0.f, 0.f, 0.f, 0.f, 0.f, 0.f, 0.f,
                    0.f, 0.f, 0.f, 0.f, 0.f, 0.f, 0.f, 0.f};
  f32x16 acc0 = Z, acc1 = Z;
  int degc = 0;
  int ng = (wend > wbase) ? ((wend - wbase + 15) >> 4) : 0;

  uint2 prA = make_uint2(0u, 0u), prB = make_uint2(0u, 0u);
  int cntA = 0, cntB = 0;
  uint4 vA0 = make_uint4(0, 0, 0, 0), vA1 = vA0, vB0 = vA0, vB1 = vA0;
  if (ng > 0) {
    prA = srt[min(wbase + (lane & 15), nE - 1)];
    cntA = min(wend - wbase, 16);
    int s0 = __shfl((int)prA.y, o), s1 = __shfl((int)prA.y, 8 + o);
    vA0 = *(const uint4*)(t1 + (size_t)((o < cntA) ? s0 : 0) * 64 + j8 * 8);
    vA1 = *(const uint4*)(t1 + (size_t)((8 + o < cntA) ? s1 : 0) * 64 + j8 * 8);
  }
  if (ng > 1) {
    int nb = wbase + 16;
    prB = srt[min(nb + (lane & 15), nE - 1)];
    cntB = min(wend - nb, 16);
    int s0 = __shfl((int)prB.y, o), s1 = __shfl((int)prB.y, 8 + o);
    vB0 = *(const uint4*)(t1 + (size_t)((o < cntB) ? s0 : 0) * 64 + j8 * 8);
    vB1 = *(const uint4*)(t1 + (size_t)((8 + o < cntB) ? s1 : 0) * 64 + j8 * 8);
  }

  for (int gg = 0; gg < ng; gg += 2) {
    bool hasB = (gg + 1 < ng);
    *(uint4*)(stA + o * TROW + j8 * 8) = vA0;
    *(uint4*)(stA + (8 + o) * TROW + j8 * 8) = vA1;
    if (hasB) {
      *(uint4*)(stB + o * TROW + j8 * 8) = vB0;
      *(uint4*)(stB + (8 + o) * TROW + j8 * 8) = vB1;
    }
    unsigned amA[8], amB[8];
#pragma unroll
    for (int m = 0; m < 8; ++m) {
      int e = 8 * hi + m;
      int dv = __shfl((int)prA.x, e);
      bool ok = (e < cntA) && ((dv & 31) == l31);
      amA[m] = ok ? 0x3F80u : 0u;
      degc += (amA[m] >> 7) & 1;
    }
    if (hasB) {
#pragma unroll
      for (int m = 0; m < 8; ++m) {
        int e = 8 * hi + m;
        int dv = __shfl((int)prB.x, e);
        bool ok = (e < cntB) && ((dv & 31) == l31);
        amB[m] = ok ? 0x3F80u : 0u;
        degc += (amB[m] >> 7) & 1;
      }
    }
    if (gg + 2 < ng) {
      int nb = wbase + (gg + 2) * 16;
      prA = srt[min(nb + (lane & 15), nE - 1)];
      cntA = min(wend - nb, 16);
      int s0 = __shfl((int)prA.y, o), s1 = __shfl((int)prA.y, 8 + o);
      vA0 = *(const uint4*)(t1 + (size_t)((o < cntA) ? s0 : 0) * 64 + j8 * 8);
      vA1 = *(const uint4*)(t1 + (size_t)((8 + o < cntA) ? s1 : 0) * 64 + j8 * 8);
    }
    if (gg + 3 < ng) {
      int nb = wbase + (gg + 3) * 16;
      prB = srt[min(nb + (lane & 15), nE - 1)];
      cntB = min(wend - nb, 16);
      int s0 = __shfl((int)prB.y, o), s1 = __shfl((int)prB.y, 8 + o);
      vB0 = *(const uint4*)(t1 + (size_t)((o < cntB) ? s0 : 0) * 64 + j8 * 8);
      vB1 = *(const uint4*)(t1 + (size_t)((8 + o < cntB) ? s1 : 0) * 64 + j8 * 8);
    }
    {
      Pack8 I;
      I.u.x = amA[0] | (amA[1] << 16);
      I.u.y = amA[2] | (amA[3] << 16);
      I.u.z = amA[4] | (amA[5] << 16);
      I.u.w = amA[6] | (amA[7] << 16);
      unsigned short b0[8], b1[8];
#pragma unroll
      for (int m = 0; m < 8; ++m) {
        b0[m] = stA[(8 * hi + m) * TROW + l31];
        b1[m] = stA[(8 * hi + m) * TROW + 32 + l31];
      }
      Pack8 F0, F1;
      F0.u.x = b0[0] | ((unsigned)b0[1] << 16);
      F0.u.y = b0[2] | ((unsigned)b0[3] << 16);
      F0.u.z = b0[4] | ((unsigned)b0[5] << 16);
      F0.u.w = b0[6] | ((unsigned)b0[7] << 16);
      F1.u.x = b1[0] | ((unsigned)b1[1] << 16);
      F1.u.y = b1[2] | ((unsigned)b1[3] << 16);
      F1.u.z = b1[4] | ((unsigned)b1[5] << 16);
      F1.u.w = b1[6] | ((unsigned)b1[7] << 16);
      acc0 = __builtin_amdgcn_mfma_f32_32x32x16_bf16(F0.s, I.s, acc0, 0, 0, 0);
      acc1 = __builtin_amdgcn_mfma_f32_32x32x16_bf16(F1.s, I.s, acc1, 0, 0, 0);
    }
    if (hasB) {
      Pack8 I;
      I.u.x = amB[0] | (amB[1] << 16);
      I.u.y = amB[2] | (amB[3] << 16);
      I.u.z = amB[4] | (amB[5] << 16);
      I.u.w = amB[6] | (amB[7] << 16);
      unsigned short b0[8], b1[8];
#pragma unroll
      for (int m = 0; m < 8; ++m) {
        b0[m] = stB[(8 * hi + m) * TROW + l31];
        b1[m] = stB[(8 * hi + m) * TROW + 32 + l31];
      }
      Pack8 F0, F1;
      F0.u.x = b0[0] | ((unsigned)b0[1] << 16);
      F0.u.y = b0[2] | ((unsigned)b0[3] << 16);
      F0.u.z = b0[4] | ((unsigned)b0[5] << 16);
      F0.u.w = b0[6] | ((unsigned)b0[7] << 16);
      F1.u.x = b1[0] | ((unsigned)b1[1] << 16);
      F1.u.y = b1[2] | ((unsigned)b1[3] << 16);
      F1.u.z = b1[4] | ((unsigned)b1[5] << 16);
      F1.u.w = b1[6] | ((unsigned)b1[7] << 16);
      acc0 = __builtin_amdgcn_mfma_f32_32x32x16_bf16(F0.s, I.s, acc0, 0, 0, 0);
      acc1 = __builtin_amdgcn_mfma_f32_32x32x16_bf16(F1.s, I.s, acc1, 0, 0, 0);
    }
  }

  ideg[w][lane] = degc;
  __syncthreads();
  float* red = (float*)&stg[0][0][0];
  for (int r = 1; r < 4; ++r) {
    if (w == r) {
#pragma unroll
      for (int i = 0; i < 16; ++i) {
        red[i * 64 + lane] = acc0[i];
        red[(16 + i) * 64 + lane] = acc1[i];
      }
    }
    __syncthreads();
    if (w == 0) {
#pragma unroll
      for (int i = 0; i < 16; ++i) {
        acc0[i] += red[i * 64 + lane];
        acc1[i] += red[(16 + i) * 64 + lane];
      }
    }
    __syncthreads();
  }

  if (w == 0) {
    int dtot = ideg[0][lane] + ideg[1][lane] + ideg[2][lane] + ideg[3][lane];
    float degf = (float)(dtot + __shfl_xor(dtot, 32));
    float inv = 1.f / fmaxf(degf, 1.f);
    int node = tile * 32 + l31;
    float d0 = 0.f, d1 = 0.f, d2 = 0.f, d3 = 0.f;
#pragma unroll
    for (int fb = 0; fb < 2; ++fb) {
#pragma unroll
      for (int q4 = 0; q4 < 4; ++q4) {
        int f0 = fb * 32 + q4 * 8 + 4 * hi;
        uint2 rv = *(const uint2*)(r1b + (size_t)node * 64 + f0);
        float bias[4] = {BF_LO(rv.x), BF_HI(rv.x), BF_LO(rv.y), BF_HI(rv.y)};
#pragma unroll
        for (int j = 0; j < 4; ++j) {
          float a = fb ? acc1[q4 * 4 + j] : acc0[q4 * 4 + j];
          float hv = fmaxf(fmaf(a, inv, bias[j]), 0.f);
          int f = f0 + j;
          d0 = fmaf(hv, pAB[0][f], d0);
          d1 = fmaf(hv, pAB[1][f], d1);
          d2 = fmaf(hv, pAB[2][f], d2);
          d3 = fmaf(hv, pAB[3][f], d3);
        }
      }
    }
    d0 += __shfl_xor(d0, 32);
    d1 += __shfl_xor(d1, 32);
    d2 += __shfl_xor(d2, 32);
    d3 += __shfl_xor(d3, 32);
    if (hi == 0) {
      g2[node] = make_float2(d0, d1);
      s2[node] = make_float2(d2, d3);
    }
  }
}

// ---------- gather2: out[n] = mean_j(g2[j]) + s2[n] + bf ----------
__global__ __launch_bounds__(256) void gather2_kernel(
    const int* __restrict__ rowstart, const int* __restrict__ degI,
    const uint2* __restrict__ srt, const float2* __restrict__ g2,
    const float2* __restrict__ s2, const float* __restrict__ bfv,
    float* __restrict__ out, int nE) {
  int tid = threadIdx.x, lane = tid & 63;
  int q = lane >> 4, l16 = lane & 15;
  float bf0 = bfv[0], bf1 = bfv[1];
  int gq = ((blockIdx.x * 256 + tid) >> 6) * 4 + q;
  int strideN = ((gridDim.x * 256) >> 6) * 4;
  for (int n = gq; n < N_NODES; n += strideN) {
    int rs = rowstart[n], dg = degI[n];
    float s0 = 0.f, s1 = 0.f;
    for (int base = 0; base < dg; base += 16) {
      int e = base + l16;
      int a = (int)srt[min(rs + ((e < dg) ? e : 0), nE - 1)].y;
      float2 v = g2[a];
      float m = (e < dg) ? 1.f : 0.f;
      s0 = fmaf(v.x, m, s0);
      s1 = fmaf(v.y, m, s1);
    }
    s0 += __shfl_xor(s0, 1); s0 += __shfl_xor(s0, 2);
    s0 += __shfl_xor(s0, 4); s0 += __shfl_xor(s0, 8);
    s1 += __shfl_xor(s1, 1); s1 += __shfl_xor(s1, 2);
    s1 += __shfl_xor(s1, 4); s1 += __shfl_xor(s1, 8);
    if (l16 == 0) {
      float inv = 1.f / (float)max(dg, 1);
      float2 sv = s2[n];
      out[(size_t)n * 2 + 0] = fmaf(s0, inv, sv.x) + bf0;
      out[(size_t)n * 2 + 1] = fmaf(s1, inv, sv.y) + bf1;
    }
  }
}

extern "C" void kernel_launch(void* const* d_in, const int* in_sizes, int n_in,
                              void* d_out, int out_size, void* d_ws,
                              size_t ws_size, hipStream_t stream) {
  const float* x   = (const float*)d_in[0];
  const int*   ei  = (const int*)d_in[1];
  const float* Wl1 = (const float*)d_in[2];
  const float* bl1 = (const float*)d_in[3];
  const float* Wr1 = (const float*)d_in[4];
  const float* Wl2 = (const float*)d_in[5];
  const float* bl2 = (const float*)d_in[6];
  const float* Wr2 = (const float*)d_in[7];
  const float* Wc  = (const float*)d_in[8];
  const float* bc  = (const float*)d_in[9];
  float* out = (float*)d_out;

  int nE = in_sizes[1] / 2;
  const int* src = ei;
  const int* dst = ei + nE;

  // Workspace (~47 MB, NO aliasing — passD reads pairs while transform
  // writes t1 in the same fused dispatch): pairs uint2[E] | srt uint2[E] |
  // t1 bf16[N*64] | r1b bf16[N*64] | g2,s2 f2[N] | A2/B2/bf | wcat |
  // degI,rowstart [N] | gcnt[100k] | csum[1024]
  uint2* pairs = (uint2*)d_ws;
  uint2* srt = pairs + nE;
  unsigned short* t1 = (unsigned short*)(srt + nE);
  unsigned short* r1b = t1 + (size_t)N_NODES * D;
  float2* g2 = (float2*)(r1b + (size_t)N_NODES * D);
  float2* s2 = g2 + N_NODES;
  float* A2 = (float*)(s2 + N_NODES);
  float* B2 = A2 + 128;
  float* bfv = B2 + 128;
  unsigned short* wcat = (unsigned short*)(bfv + 4);
  int* degI = (int*)(wcat + 8192);
  int* rowstart = degI + N_NODES;
  int* gcnt = rowstart + N_NODES;
  int* csum = gcnt + GCNT_N;

  int ec = (nE + NBLK_A - 1) / NBLK_A;

  passA_count<<<NBLK_A, 256, 0, stream>>>(dst, gcnt, nE, ec);
  gscan_p1<<<NCHUNK, 256, 0, stream>>>(gcnt, csum);
  gscan_p2<<<1, 1024, 0, stream>>>(csum, NCHUNK);
  gscan_p3<<<NCHUNK, 256, 0, stream>>>(gcnt, csum);
  passC_prep<<<NBLK_A + 1, 256, 0, stream>>>(src, dst, gcnt, pairs, nE, ec,
                                             Wc, Wl2, Wr2, bl2, bc, Wl1, Wr1,
                                             A2, B2, bfv, wcat);
  passD_transform<<<NBUCK + TBLK, 256, 0, stream>>>(pairs, gcnt, rowstart,
                                                    degI, srt, nE, x, wcat,
                                                    bl1, t1, r1b);
  tile_g1<<<NTILES, 256, 0, stream>>>(srt, rowstart, t1, r1b, A2, B2, g2, s2,
                                      nE);
  gather2_kernel<<<512, 256, 0, stream>>>(rowstart, degI, srt, g2, s2, bfv,
                                          out, nE);
}

// Round 16
// 124.632 us; speedup vs baseline: 5.0685x; 1.0523x over previous
//
#include <hip/hip_runtime.h>

#define N_NODES 100000
#define D 64
#define NTILES 3125       // 32-node output tiles for tile_g1
#define NBUCK 391         // 256-node buckets: dst>>8
#define NBLK_A 256        // blocks in count/place passes
#define GCNT_N (NBUCK * NBLK_A)            // 100096
#define NCHUNK ((GCNT_N + 255) / 256)      // 391
#define NTILE_T (N_NODES / 32)             // transform tiles
#define TROW 72           // staged row stride in bf16 elems (144B)
#define TBLK 512          // transform blocks inside fused kernel

typedef __attribute__((ext_vector_type(8))) short short8;
typedef __attribute__((ext_vector_type(16))) float f32x16;
union Pack8 { uint4 u; short8 s; };

__device__ __forceinline__ unsigned f2bf(float f) {  // RNE float->bf16 bits
  unsigned u = __float_as_uint(f);
  return (u + 0x7fffu + ((u >> 16) & 1u)) >> 16;
}
#define BF_LO(u) __uint_as_float(((unsigned)(u)) << 16)
#define BF_HI(u) __uint_as_float(((unsigned)(u)) & 0xffff0000u)

// Packed edge record: bits 31..24 = dst&255 (bucket-local), bits 23..0 = src.

// ---------- counting-sort to 256-node buckets ----------

__global__ __launch_bounds__(256) void passA_count(const int* __restrict__ dst,
                                                   int* __restrict__ gcnt,
                                                   int nE, int ec) {
  __shared__ int cnt[NBUCK];
  int t = threadIdx.x, blk = blockIdx.x;
  for (int i = t; i < NBUCK; i += 256) cnt[i] = 0;
  __syncthreads();
  int e0 = blk * ec, e1 = min(e0 + ec, nE);
  for (int e = e0 + t; e < e1; e += 256) atomicAdd(&cnt[dst[e] >> 8], 1);
  __syncthreads();
  for (int b = t; b < NBUCK; b += 256) gcnt[b * NBLK_A + blk] = cnt[b];
}

__global__ void gscan_p1(const int* __restrict__ g, int* __restrict__ csum) {
  int t = threadIdx.x, b = blockIdx.x;
  int i = b * 256 + t;
  int v = (i < GCNT_N) ? g[i] : 0;
  for (int off = 32; off; off >>= 1) v += __shfl_down(v, off);
  __shared__ int ws4[4];
  if ((t & 63) == 0) ws4[t >> 6] = v;
  __syncthreads();
  if (t == 0) csum[b] = ws4[0] + ws4[1] + ws4[2] + ws4[3];
}

__global__ void gscan_p2(int* __restrict__ csum, int nB) {
  __shared__ int s[1024];
  int t = threadIdx.x;
  int orig = (t < nB) ? csum[t] : 0;
  s[t] = orig;
  __syncthreads();
  for (int off = 1; off < 1024; off <<= 1) {
    int v = (t >= off) ? s[t - off] : 0;
    __syncthreads();
    s[t] += v;
    __syncthreads();
  }
  if (t < nB) csum[t] = s[t] - orig;  // exclusive block offsets
}

__global__ void gscan_p3(int* __restrict__ g, const int* __restrict__ csum) {
  __shared__ int s[256];
  int t = threadIdx.x, b = blockIdx.x;
  int i = b * 256 + t;
  int d = (i < GCNT_N) ? g[i] : 0;
  s[t] = d;
  __syncthreads();
  for (int off = 1; off < 256; off <<= 1) {
    int v = (t >= off) ? s[t - off] : 0;
    __syncthreads();
    s[t] += v;
    __syncthreads();
  }
  if (i < GCNT_N) g[i] = s[t] - d + csum[b];  // exclusive
}

// ---------- passC (blocks 0..NBLK_A-1) + prep (block NBLK_A) fused ----------
__global__ __launch_bounds__(256) void passC_prep(
    const int* __restrict__ src, const int* __restrict__ dst,
    const int* __restrict__ S, unsigned* __restrict__ pairs4, int nE, int ec,
    const float* __restrict__ Wc, const float* __restrict__ Wl2,
    const float* __restrict__ Wr2, const float* __restrict__ bl2,
    const float* __restrict__ bc, const float* __restrict__ Wl1,
    const float* __restrict__ Wr1, float* __restrict__ A2,
    float* __restrict__ B2, float* __restrict__ bfv,
    unsigned short* __restrict__ wcat) {
  __shared__ int cur[NBUCK];
  int t = threadIdx.x, blk = blockIdx.x;
  if (blk < NBLK_A) {
    for (int b = t; b < NBUCK; b += 256) cur[b] = S[b * NBLK_A + blk];
    __syncthreads();
    int e0 = blk * ec, e1 = min(e0 + ec, nE);
    for (int e = e0 + t; e < e1; e += 256) {
      int d = dst[e];
      int p = atomicAdd(&cur[d >> 8], 1);
      pairs4[p] = ((unsigned)(d & 255) << 24) | (unsigned)src[e];
    }
  } else {
    for (int i = t; i < 8192; i += 256)
      wcat[i] = (unsigned short)f2bf((i < 4096) ? Wl1[i] : Wr1[i - 4096]);
    if (t < 128) {
      int c = t >> 6, k = t & 63;
      float sa = 0.f, sb = 0.f;
      for (int j = 0; j < 64; ++j) {
        float w = Wc[c * 64 + j];
        sa = fmaf(w, Wl2[j * 64 + k], sa);
        sb = fmaf(w, Wr2[j * 64 + k], sb);
      }
      A2[c * 64 + k] = sa;
      B2[c * 64 + k] = sb;
    }
    if (t < 2) {
      float s = bc[t];
      for (int j = 0; j < 64; ++j) s = fmaf(Wc[t * 64 + j], bl2[j], s);
      bfv[t] = s;
    }
  }
}

// ---------- fused: tile-sort passD (blocks 0..NBUCK-1) + transform ----------
// passD now sorts only to 32-node-tile granularity (8 bins per bucket) and
// emits tstart[] tile offsets. tile_g1 derives degrees itself; gather2 works
// on bucket-sorted pairs directly -> per-node CSR no longer needed.
__global__ __launch_bounds__(256) void passD_transform(
    const unsigned* __restrict__ pairs4, const int* __restrict__ S,
    int* __restrict__ tstart, unsigned* __restrict__ srt4, int nE,
    const float* __restrict__ x, const unsigned short* __restrict__ wcat,
    const float* __restrict__ bl, unsigned short* __restrict__ t1,
    unsigned short* __restrict__ r1b) {
  __shared__ int h8[8 * 16];
  __shared__ int ex8[9];
  __shared__ int cur8[8];
  int t = threadIdx.x;
  if (blockIdx.x < NBUCK) {
    int b = blockIdx.x;
    int base = S[b * NBLK_A];
    int end = (b == NBUCK - 1) ? nE : S[(b + 1) * NBLK_A];
    if (t < 128) h8[t] = 0;
    __syncthreads();
    for (int p = base + t; p < end; p += 256)
      atomicAdd(&h8[((pairs4[p] >> 29) & 7) * 16 + (t & 15)], 1);
    __syncthreads();
    if (t == 0) {
      int run = base;
      for (int bin = 0; bin < 8; ++bin) {
        ex8[bin] = run;
        int s = 0;
        for (int i = 0; i < 16; ++i) s += h8[bin * 16 + i];
        run += s;
      }
      ex8[8] = run;
    }
    __syncthreads();
    if (t < 8) {
      cur8[t] = ex8[t];
      tstart[b * 8 + t] = ex8[t];
    }
    if (b == NBUCK - 1 && t == 0) tstart[NBUCK * 8] = nE;
    __syncthreads();
    for (int p = base + t; p < end; p += 256) {
      unsigned pk = pairs4[p];
      int slot = atomicAdd(&cur8[(pk >> 29) & 7], 1);
      srt4[slot] = pk;
    }
  } else {
    int lane = t & 63;
    int l31 = lane & 31, hi = lane >> 5;

    short8 af[4][4];
#pragma unroll
    for (int jt = 0; jt < 4; ++jt)
#pragma unroll
      for (int kk = 0; kk < 4; ++kk)
        af[jt][kk] =
            *(const short8*)(wcat + (jt * 32 + l31) * 64 + kk * 16 + 8 * hi);

    const f32x16 Z = {0.f, 0.f, 0.f, 0.f, 0.f, 0.f, 0.f, 0.f,
                      0.f, 0.f, 0.f, 0.f, 0.f, 0.f, 0.f, 0.f};
    const float4* x4 = (const float4*)x;

    int gw = ((blockIdx.x - NBUCK) * 256 + t) >> 6;
    int nW = (TBLK * 256) >> 6;

    for (int tile = gw; tile < NTILE_T; tile += nW) {
      int node = tile * 32 + l31;
      f32x16 acc[4] = {Z, Z, Z, Z};
#pragma unroll
      for (int kk = 0; kk < 4; ++kk) {
        float4 fa = x4[(size_t)node * 16 + kk * 4 + 2 * hi];
        float4 fb = x4[(size_t)node * 16 + kk * 4 + 2 * hi + 1];
        Pack8 pk;
        pk.u.x = f2bf(fa.x) | (f2bf(fa.y) << 16);
        pk.u.y = f2bf(fa.z) | (f2bf(fa.w) << 16);
        pk.u.z = f2bf(fb.x) | (f2bf(fb.y) << 16);
        pk.u.w = f2bf(fb.z) | (f2bf(fb.w) << 16);
        acc[0] = __builtin_amdgcn_mfma_f32_32x32x16_bf16(af[0][kk], pk.s, acc[0], 0, 0, 0);
        acc[1] = __builtin_amdgcn_mfma_f32_32x32x16_bf16(af[1][kk], pk.s, acc[1], 0, 0, 0);
        acc[2] = __builtin_amdgcn_mfma_f32_32x32x16_bf16(af[2][kk], pk.s, acc[2], 0, 0, 0);
        acc[3] = __builtin_amdgcn_mfma_f32_32x32x16_bf16(af[3][kk], pk.s, acc[3], 0, 0, 0);
      }
#pragma unroll
      for (int jt = 0; jt < 2; ++jt)
#pragma unroll
        for (int rg = 0; rg < 4; ++rg) {
          int j0 = jt * 32 + 8 * rg + 4 * hi;
          uint2 p;
          p.x = f2bf(acc[jt][4 * rg + 0]) | (f2bf(acc[jt][4 * rg + 1]) << 16);
          p.y = f2bf(acc[jt][4 * rg + 2]) | (f2bf(acc[jt][4 * rg + 3]) << 16);
          *(uint2*)(t1 + (size_t)node * 64 + j0) = p;
        }
#pragma unroll
      for (int jt = 2; jt < 4; ++jt)
#pragma unroll
        for (int rg = 0; rg < 4; ++rg) {
          int j0 = (jt - 2) * 32 + 8 * rg + 4 * hi;
          float4 bv = ((const float4*)bl)[j0 >> 2];
          uint2 p;
          p.x = f2bf(acc[jt][4 * rg + 0] + bv.x) |
                (f2bf(acc[jt][4 * rg + 1] + bv.y) << 16);
          p.y = f2bf(acc[jt][4 * rg + 2] + bv.z) |
                (f2bf(acc[jt][4 * rg + 3] + bv.w) << 16);
          *(uint2*)(r1b + (size_t)node * 64 + j0) = p;
        }
    }
  }
}

// ---------- tile_g1: MFMA indicator-gather, 4 waves per tile ----------
__global__ __launch_bounds__(256) void tile_g1(
    const unsigned* __restrict__ srt4, const int* __restrict__ tstart,
    const unsigned short* __restrict__ t1,
    const unsigned short* __restrict__ r1b, const float* __restrict__ A2,
    const float* __restrict__ B2, float2* __restrict__ g2,
    float2* __restrict__ s2, int nE) {
  __shared__ float pAB[4][64];
  __shared__ unsigned short stg[4][2][16 * TROW];
  __shared__ int ideg[4][64];
  int t = threadIdx.x, lane = t & 63, w = t >> 6;
  pAB[t >> 6][t & 63] = (t < 128) ? A2[t] : B2[t - 128];
  __syncthreads();

  int tile = blockIdx.x;
  int base = tstart[tile];
  int end = tstart[tile + 1];
  int l31 = lane & 31, hi = lane >> 5;
  int o = lane >> 3, j8 = lane & 7;
  unsigned short* stA = &stg[w][0][0];
  unsigned short* stB = &stg[w][1][0];

  int ngAll = (end > base) ? ((end - base + 15) >> 4) : 0;
  int gper = (ngAll + 3) >> 2;
  int wbase = base + min(w * gper, ngAll) * 16;
  int wend = min(base + min((w + 1) * gper, ngAll) * 16, end);

  const f32x16 Z = {0.f, 0.f, 0.f, 0.f, 0.f, 0.f, 0.f, 0.f,
                    0.f, 0.f, 0.f, 0.f, 0.f, 0.f, 0.f, 0.f};
  f32x16 acc0 = Z, acc1 = Z;
  int degc = 0;
  int ng = (wend > wbase) ? ((wend - wbase + 15) >> 4) : 0;

  unsigned pkA = 0u, pkB = 0u;
  int cntA = 0, cntB = 0;
  uint4 vA0 = make_uint4(0, 0, 0, 0), vA1 = vA0, vB0 = vA0, vB1 = vA0;
  if (ng > 0) {
    pkA = srt4[min(wbase + (lane & 15), nE - 1)];
    cntA = min(wend - wbase, 16);
    int s0 = __shfl((int)pkA, o) & 0xFFFFFF;
    int s1 = __shfl((int)pkA, 8 + o) & 0xFFFFFF;
    vA0 = *(const uint4*)(t1 + (size_t)((o < cntA) ? s0 : 0) * 64 + j8 * 8);
    vA1 = *(const uint4*)(t1 + (size_t)((8 + o < cntA) ? s1 : 0) * 64 + j8 * 8);
  }
  if (ng > 1) {
    int nb = wbase + 16;
    pkB = srt4[min(nb + (lane & 15), nE - 1)];
    cntB = min(wend - nb, 16);
    int s0 = __shfl((int)pkB, o) & 0xFFFFFF;
    int s1 = __shfl((int)pkB, 8 + o) & 0xFFFFFF;
    vB0 = *(const uint4*)(t1 + (size_t)((o < cntB) ? s0 : 0) * 64 + j8 * 8);
    vB1 = *(const uint4*)(t1 + (size_t)((8 + o < cntB) ? s1 : 0) * 64 + j8 * 8);
  }

  for (int gg = 0; gg < ng; gg += 2) {
    bool hasB = (gg + 1 < ng);
    *(uint4*)(stA + o * TROW + j8 * 8) = vA0;
    *(uint4*)(stA + (8 + o) * TROW + j8 * 8) = vA1;
    if (hasB) {
      *(uint4*)(stB + o * TROW + j8 * 8) = vB0;
      *(uint4*)(stB + (8 + o) * TROW + j8 * 8) = vB1;
    }
    unsigned amA[8], amB[8];
#pragma unroll
    for (int m = 0; m < 8; ++m) {
      int e = 8 * hi + m;
      int pv = __shfl((int)pkA, e);
      bool ok = (e < cntA) && (((pv >> 24) & 31) == l31);
      amA[m] = ok ? 0x3F80u : 0u;
      degc += (amA[m] >> 7) & 1;
    }
    if (hasB) {
#pragma unroll
      for (int m = 0; m < 8; ++m) {
        int e = 8 * hi + m;
        int pv = __shfl((int)pkB, e);
        bool ok = (e < cntB) && (((pv >> 24) & 31) == l31);
        amB[m] = ok ? 0x3F80u : 0u;
        degc += (amB[m] >> 7) & 1;
      }
    }
    if (gg + 2 < ng) {
      int nb = wbase + (gg + 2) * 16;
      pkA = srt4[min(nb + (lane & 15), nE - 1)];
      cntA = min(wend - nb, 16);
      int s0 = __shfl((int)pkA, o) & 0xFFFFFF;
      int s1 = __shfl((int)pkA, 8 + o) & 0xFFFFFF;
      vA0 = *(const uint4*)(t1 + (size_t)((o < cntA) ? s0 : 0) * 64 + j8 * 8);
      vA1 = *(const uint4*)(t1 + (size_t)((8 + o < cntA) ? s1 : 0) * 64 + j8 * 8);
    }
    if (gg + 3 < ng) {
      int nb = wbase + (gg + 3) * 16;
      pkB = srt4[min(nb + (lane & 15), nE - 1)];
      cntB = min(wend - nb, 16);
      int s0 = __shfl((int)pkB, o) & 0xFFFFFF;
      int s1 = __shfl((int)pkB, 8 + o) & 0xFFFFFF;
      vB0 = *(const uint4*)(t1 + (size_t)((o < cntB) ? s0 : 0) * 64 + j8 * 8);
      vB1 = *(const uint4*)(t1 + (size_t)((8 + o < cntB) ? s1 : 0) * 64 + j8 * 8);
    }
    {
      Pack8 I;
      I.u.x = amA[0] | (amA[1] << 16);
      I.u.y = amA[2] | (amA[3] << 16);
      I.u.z = amA[4] | (amA[5] << 16);
      I.u.w = amA[6] | (amA[7] << 16);
      unsigned short b0[8], b1[8];
#pragma unroll
      for (int m = 0; m < 8; ++m) {
        b0[m] = stA[(8 * hi + m) * TROW + l31];
        b1[m] = stA[(8 * hi + m) * TROW + 32 + l31];
      }
      Pack8 F0, F1;
      F0.u.x = b0[0] | ((unsigned)b0[1] << 16);
      F0.u.y = b0[2] | ((unsigned)b0[3] << 16);
      F0.u.z = b0[4] | ((unsigned)b0[5] << 16);
      F0.u.w = b0[6] | ((unsigned)b0[7] << 16);
      F1.u.x = b1[0] | ((unsigned)b1[1] << 16);
      F1.u.y = b1[2] | ((unsigned)b1[3] << 16);
      F1.u.z = b1[4] | ((unsigned)b1[5] << 16);
      F1.u.w = b1[6] | ((unsigned)b1[7] << 16);
      acc0 = __builtin_amdgcn_mfma_f32_32x32x16_bf16(F0.s, I.s, acc0, 0, 0, 0);
      acc1 = __builtin_amdgcn_mfma_f32_32x32x16_bf16(F1.s, I.s, acc1, 0, 0, 0);
    }
    if (hasB) {
      Pack8 I;
      I.u.x = amB[0] | (amB[1] << 16);
      I.u.y = amB[2] | (amB[3] << 16);
      I.u.z = amB[4] | (amB[5] << 16);
      I.u.w = amB[6] | (amB[7] << 16);
      unsigned short b0[8], b1[8];
#pragma unroll
      for (int m = 0; m < 8; ++m) {
        b0[m] = stB[(8 * hi + m) * TROW + l31];
        b1[m] = stB[(8 * hi + m) * TROW + 32 + l31];
      }
      Pack8 F0, F1;
      F0.u.x = b0[0] | ((unsigned)b0[1] << 16);
      F0.u.y = b0[2] | ((unsigned)b0[3] << 16);
      F0.u.z = b0[4] | ((unsigned)b0[5] << 16);
      F0.u.w = b0[6] | ((unsigned)b0[7] << 16);
      F1.u.x = b1[0] | ((unsigned)b1[1] << 16);
      F1.u.y = b1[2] | ((unsigned)b1[3] << 16);
      F1.u.z = b1[4] | ((unsigned)b1[5] << 16);
      F1.u.w = b1[6] | ((unsigned)b1[7] << 16);
      acc0 = __builtin_amdgcn_mfma_f32_32x32x16_bf16(F0.s, I.s, acc0, 0, 0, 0);
      acc1 = __builtin_amdgcn_mfma_f32_32x32x16_bf16(F1.s, I.s, acc1, 0, 0, 0);
    }
  }

  ideg[w][lane] = degc;
  __syncthreads();
  float* red = (float*)&stg[0][0][0];
  for (int r = 1; r < 4; ++r) {
    if (w == r) {
#pragma unroll
      for (int i = 0; i < 16; ++i) {
        red[i * 64 + lane] = acc0[i];
        red[(16 + i) * 64 + lane] = acc1[i];
      }
    }
    __syncthreads();
    if (w == 0) {
#pragma unroll
      for (int i = 0; i < 16; ++i) {
        acc0[i] += red[i * 64 + lane];
        acc1[i] += red[(16 + i) * 64 + lane];
      }
    }
    __syncthreads();
  }

  if (w == 0) {
    int dtot = ideg[0][lane] + ideg[1][lane] + ideg[2][lane] + ideg[3][lane];
    float degf = (float)(dtot + __shfl_xor(dtot, 32));
    float inv = 1.f / fmaxf(degf, 1.f);
    int node = tile * 32 + l31;
    float d0 = 0.f, d1 = 0.f, d2 = 0.f, d3 = 0.f;
#pragma unroll
    for (int fb = 0; fb < 2; ++fb) {
#pragma unroll
      for (int q4 = 0; q4 < 4; ++q4) {
        int f0 = fb * 32 + q4 * 8 + 4 * hi;
        uint2 rv = *(const uint2*)(r1b + (size_t)node * 64 + f0);
        float bias[4] = {BF_LO(rv.x), BF_HI(rv.x), BF_LO(rv.y), BF_HI(rv.y)};
#pragma unroll
        for (int j = 0; j < 4; ++j) {
          float a = fb ? acc1[q4 * 4 + j] : acc0[q4 * 4 + j];
          float hv = fmaxf(fmaf(a, inv, bias[j]), 0.f);
          int f = f0 + j;
          d0 = fmaf(hv, pAB[0][f], d0);
          d1 = fmaf(hv, pAB[1][f], d1);
          d2 = fmaf(hv, pAB[2][f], d2);
          d3 = fmaf(hv, pAB[3][f], d3);
        }
      }
    }
    d0 += __shfl_xor(d0, 32);
    d1 += __shfl_xor(d1, 32);
    d2 += __shfl_xor(d2, 32);
    d3 += __shfl_xor(d3, 32);
    if (hi == 0) {
      g2[node] = make_float2(d0, d1);
      s2[node] = make_float2(d2, d3);
    }
  }
}

// ---------- bucket_g2: per-bucket LDS accumulation of g2 -> out ----------
// One block per 256-node bucket; reads bucket-sorted packed pairs directly
// (no per-node sort needed). 3 LDS atomics/edge over 256 slots: trivial
// contention (~12 ops/address).
__global__ __launch_bounds__(256) void bucket_g2(
    const unsigned* __restrict__ pairs4, const int* __restrict__ S,
    const float2* __restrict__ g2, const float2* __restrict__ s2,
    const float* __restrict__ bfv, float* __restrict__ out, int nE) {
  __shared__ float o0[256], o1[256];
  __shared__ int cnt[256];
  int t = threadIdx.x, b = blockIdx.x;
  o0[t] = 0.f;
  o1[t] = 0.f;
  cnt[t] = 0;
  __syncthreads();
  int base = S[b * NBLK_A];
  int end = (b == NBUCK - 1) ? nE : S[(b + 1) * NBLK_A];
  for (int p = base + t; p < end; p += 256) {
    unsigned pk = pairs4[p];
    float2 v = g2[pk & 0xFFFFFFu];
    int dl = pk >> 24;
    atomicAdd(&o0[dl], v.x);
    atomicAdd(&o1[dl], v.y);
    atomicAdd(&cnt[dl], 1);
  }
  __syncthreads();
  int node = b * 256 + t;
  if (node < N_NODES) {
    float inv = 1.f / (float)max(cnt[t], 1);
    float2 sv = s2[node];
    out[(size_t)node * 2 + 0] = fmaf(o0[t], inv, sv.x) + bfv[0];
    out[(size_t)node * 2 + 1] = fmaf(o1[t], inv, sv.y) + bfv[1];
  }
}

extern "C" void kernel_launch(void* const* d_in, const int* in_sizes, int n_in,
                              void* d_out, int out_size, void* d_ws,
                              size_t ws_size, hipStream_t stream) {
  const float* x   = (const float*)d_in[0];
  const int*   ei  = (const int*)d_in[1];
  const float* Wl1 = (const float*)d_in[2];
  const float* bl1 = (const float*)d_in[3];
  const float* Wr1 = (const float*)d_in[4];
  const float* Wl2 = (const float*)d_in[5];
  const float* bl2 = (const float*)d_in[6];
  const float* Wr2 = (const float*)d_in[7];
  const float* Wc  = (const float*)d_in[8];
  const float* bc  = (const float*)d_in[9];
  float* out = (float*)d_out;

  int nE = in_sizes[1] / 2;
  const int* src = ei;
  const int* dst = ei + nE;

  // Workspace (~37 MB, no aliasing): pairs4 u32[E] | srt4 u32[E] |
  // t1 bf16[N*64] | r1b bf16[N*64] | g2,s2 f2[N] | A2/B2/bf | wcat |
  // tstart[NBUCK*8+1] | gcnt[100k] | csum[1024]
  unsigned* pairs4 = (unsigned*)d_ws;
  unsigned* srt4 = pairs4 + nE;
  unsigned short* t1 = (unsigned short*)(srt4 + nE);
  unsigned short* r1b = t1 + (size_t)N_NODES * D;
  float2* g2 = (float2*)(r1b + (size_t)N_NODES * D);
  float2* s2 = g2 + N_NODES;
  float* A2 = (float*)(s2 + N_NODES);
  float* B2 = A2 + 128;
  float* bfv = B2 + 128;
  unsigned short* wcat = (unsigned short*)(bfv + 4);
  int* tstart = (int*)(wcat + 8192);
  int* gcnt = tstart + (NBUCK * 8 + 2);
  int* csum = gcnt + GCNT_N;

  int ec = (nE + NBLK_A - 1) / NBLK_A;

  passA_count<<<NBLK_A, 256, 0, stream>>>(dst, gcnt, nE, ec);
  gscan_p1<<<NCHUNK, 256, 0, stream>>>(gcnt, csum);
  gscan_p2<<<1, 1024, 0, stream>>>(csum, NCHUNK);
  gscan_p3<<<NCHUNK, 256, 0, stream>>>(gcnt, csum);
  passC_prep<<<NBLK_A + 1, 256, 0, stream>>>(src, dst, gcnt, pairs4, nE, ec,
                                             Wc, Wl2, Wr2, bl2, bc, Wl1, Wr1,
                                             A2, B2, bfv, wcat);
  passD_transform<<<NBUCK + TBLK, 256, 0, stream>>>(pairs4, gcnt, tstart,
                                                    srt4, nE, x, wcat, bl1,
                                                    t1, r1b);
  tile_g1<<<NTILES, 256, 0, stream>>>(srt4, tstart, t1, r1b, A2, B2, g2, s2,
                                      nE);
  bucket_g2<<<NBUCK, 256, 0, stream>>>(pairs4, gcnt, g2, s2, bfv, out, nE);
}